// Round 5
// baseline (11348.657 us; speedup 1.0000x reference)
//
#include <hip/hip_runtime.h>
#include <hip/hip_bf16.h>

#define BB 32
#define TT 128
#define PP 196
#define PPAD 208
#define ENC 2048
#define DEC 512
#define ATT 512
#define EMB 512
#define VV 10000
#define VVP 10240
#define G4 2048
#define KX 2560
#define NWG 256

typedef unsigned short u16;
typedef unsigned int u32;
typedef __attribute__((ext_vector_type(8))) short short8;
typedef __attribute__((ext_vector_type(4))) float f32x4;

__device__ __forceinline__ float bf2f(u16 u) { return __uint_as_float(((u32)u) << 16); }
__device__ __forceinline__ u16 f2bf(float f) {
  u32 x = __float_as_uint(f);
  u32 r = (x + 0x7fffu + ((x >> 16) & 1u)) >> 16;
  return (u16)r;
}
__device__ __forceinline__ void unpack8(uint4 v, float* f) {
  f[0] = __uint_as_float(v.x << 16); f[1] = __uint_as_float(v.x & 0xffff0000u);
  f[2] = __uint_as_float(v.y << 16); f[3] = __uint_as_float(v.y & 0xffff0000u);
  f[4] = __uint_as_float(v.z << 16); f[5] = __uint_as_float(v.z & 0xffff0000u);
  f[6] = __uint_as_float(v.w << 16); f[7] = __uint_as_float(v.w & 0xffff0000u);
}
__device__ __forceinline__ void load8(const float* __restrict__ p, float* f) {
  float4 a = ((const float4*)p)[0];
  float4 b = ((const float4*)p)[1];
  f[0] = a.x; f[1] = a.y; f[2] = a.z; f[3] = a.w;
  f[4] = b.x; f[5] = b.y; f[6] = b.z; f[7] = b.w;
}
__device__ __forceinline__ float sigf(float x) { return 1.0f / (1.0f + __expf(-x)); }
__device__ __forceinline__ short8 ld_frag(const u16* __restrict__ p) {
  union { uint4 u; short8 s; } cv;
  cv.u = *(const uint4*)p;
  return cv.s;
}

// ---- device-scope relaxed atomics (LLC-coherent payload, no L2 invalidates) ----
__device__ __forceinline__ void ast_f32(float* p, float v) {
  __hip_atomic_store(p, v, __ATOMIC_RELAXED, __HIP_MEMORY_SCOPE_AGENT);
}
__device__ __forceinline__ float ald_f32(const float* p) {
  return __hip_atomic_load((float*)p, __ATOMIC_RELAXED, __HIP_MEMORY_SCOPE_AGENT);
}
__device__ __forceinline__ u32 ald_u32(const u32* p) {
  return __hip_atomic_load((u32*)p, __ATOMIC_RELAXED, __HIP_MEMORY_SCOPE_AGENT);
}
__device__ __forceinline__ void ast_u16(u16* p, u16 v) {
  __hip_atomic_store(p, v, __ATOMIC_RELAXED, __HIP_MEMORY_SCOPE_AGENT);
}

// chunk-linear addressing (chunk = one lane's ds_read_b128 payload)
__device__ __forceinline__ int hadr(int b, int d) {
  return ((((b >> 4) << 10) + ((d >> 5) << 6) + (((d >> 3) & 3) << 4) + (b & 15)) << 3) + (d & 7);
}
__device__ __forceinline__ int xadr(int b, int ch) {
  return ((((b >> 4) << 12) + ((ch >> 5) << 6) + (((ch >> 3) & 3) << 4) + (b & 15)) << 3) + (ch & 7);
}

// ---------- one-time f32 -> bf16 conversion ----------
__global__ __launch_bounds__(256) void k_cvt(const float* __restrict__ src, u16* __restrict__ dst, int n) {
  int i0 = (blockIdx.x * 256 + threadIdx.x) * 8;
  if (i0 >= n) return;
  float f[8]; load8(src + i0, f);
  u16 o[8];
#pragma unroll
  for (int u = 0; u < 8; u++) o[u] = f2bf(f[u]);
  *(uint4*)(dst + i0) = *(const uint4*)o;
}

// ---------- one-time: gather emb rows -> xemb bf16 (4096 x 512) ----------
__global__ __launch_bounds__(256) void k_emball(const int* __restrict__ bx,
    const float* __restrict__ embW, u16* __restrict__ xemb) {
  int flat = blockIdx.x * 256 + threadIdx.x;
  int row = flat >> 6;
  int c8 = (flat & 63) * 8;
  int tok = bx[row];
  const float* e = embW + (size_t)tok * EMB + c8;
  float f[8]; load8(e, f);
  u16 o[8];
#pragma unroll
  for (int u = 0; u < 8; u++) o[u] = f2bf(f[u]);
  *(uint4*)(xemb + (size_t)row * EMB + c8) = *(const uint4*)o;
}

// ---------- one-time: transpose imgs f32 -> imgsT bf16 [b][ch][p(pad 208)] ----------
__global__ __launch_bounds__(256) void k_timg(const float* __restrict__ imgs, u16* __restrict__ imgsT) {
  int b = blockIdx.x >> 8;
  int sub = blockIdx.x & 255;
  int flat = sub * 256 + threadIdx.x;
  int ch = flat >> 5, pg = flat & 31;
  if (pg >= 26) return;
  u16 o[8];
#pragma unroll
  for (int j = 0; j < 8; j++) {
    int p = pg * 8 + j;
    float v = (p < PP) ? imgs[((size_t)b * PP + p) * ENC + ch] : 0.f;
    o[j] = f2bf(v);
  }
  *(uint4*)(imgsT + ((size_t)b * 2048 + ch) * PPAD + pg * 8) = *(const uint4*)o;
}

// ---------- mean over p ----------
__global__ __launch_bounds__(256) void k_mean(const u16* __restrict__ imgs_bf, u16* __restrict__ mean_bf) {
  int b = blockIdx.x >> 2, chunk = blockIdx.x & 3;
  int ch0 = chunk * 512 + threadIdx.x * 2;
  const u32* base = (const u32*)(imgs_bf + (size_t)b * PP * ENC + ch0);
  float a0 = 0.f, a1 = 0.f;
#pragma unroll 4
  for (int p = 0; p < PP; p++) {
    u32 u = base[(size_t)p * (ENC / 2)];
    a0 += __uint_as_float(u << 16);
    a1 += __uint_as_float(u & 0xffff0000u);
  }
  const float inv = 1.0f / PP;
  u16 o[2] = { f2bf(a0 * inv), f2bf(a1 * inv) };
  *(u32*)(mean_bf + b * ENC + ch0) = *(const u32*)o;
}

// ---------- init via MFMA: h0 (chunk layout) and c0 ----------
__global__ __launch_bounds__(64) void k_init2(const u16* __restrict__ W2_bf,
    const float* __restrict__ ihb, const float* __restrict__ icb,
    const u16* __restrict__ mean_bf, u16* __restrict__ h_chunk, float* __restrict__ c) {
  int lane = threadIdx.x;
  int j0 = blockIdx.x * 16;
  int m = lane & 15, quad = lane >> 4;
  const u16* arow = W2_bf + (size_t)(j0 + m) * ENC + quad * 8;
  const u16* xb0 = mean_bf + (size_t)m * ENC + quad * 8;
  const u16* xb1 = mean_bf + (size_t)(16 + m) * ENC + quad * 8;
  f32x4 acc0 = {0.f,0.f,0.f,0.f}, acc1 = {0.f,0.f,0.f,0.f};
  for (int k = 0; k < ENC; k += 32) {
    short8 a = ld_frag(arow + k);
    short8 x0 = ld_frag(xb0 + k);
    short8 x1 = ld_frag(xb1 + k);
    acc0 = __builtin_amdgcn_mfma_f32_16x16x32_bf16(a, x0, acc0, 0, 0, 0);
    acc1 = __builtin_amdgcn_mfma_f32_16x16x32_bf16(a, x1, acc1, 0, 0, 0);
  }
  int jj = j0 + quad * 4;
  int b0 = m, b1 = 16 + m;
#pragma unroll
  for (int r = 0; r < 4; r++) {
    int j = jj + r;
    if (j < 512) {
      float bia = ihb[j];
      h_chunk[hadr(b0, j)] = f2bf(acc0[r] + bia);
      h_chunk[hadr(b1, j)] = f2bf(acc1[r] + bia);
    } else {
      int g = j - 512;
      float bia = icb[g];
      c[b0 * DEC + g] = acc0[r] + bia;
      c[b1 * DEC + g] = acc1[r] + bia;
    }
  }
}

// ---------- att1 via MFMA ----------
__global__ __launch_bounds__(256) void k_att1(const u16* __restrict__ imgs_bf,
    const u16* __restrict__ encW_bf, const float* __restrict__ encb, u16* __restrict__ att1) {
  int tid = threadIdx.x;
  int wave = tid >> 6, lane = tid & 63;
  int m0 = blockIdx.x * 32;
  int lm = lane & 15, quad = lane >> 4;
  const u16* b0p = imgs_bf + (size_t)(m0 + lm) * ENC + quad * 8;
  const u16* b1p = imgs_bf + (size_t)(m0 + 16 + lm) * ENC + quad * 8;
  const u16* arow = encW_bf + (size_t)(wave * 128 + lm) * ENC + quad * 8;
  f32x4 acc[8][2];
#pragma unroll
  for (int i = 0; i < 8; i++) { acc[i][0] = (f32x4){0.f,0.f,0.f,0.f}; acc[i][1] = (f32x4){0.f,0.f,0.f,0.f}; }
  for (int k = 0; k < ENC; k += 32) {
    short8 B0 = ld_frag(b0p + k);
    short8 B1 = ld_frag(b1p + k);
#pragma unroll
    for (int i = 0; i < 8; i++) {
      short8 A = ld_frag(arow + (size_t)i * 16 * ENC + k);
      acc[i][0] = __builtin_amdgcn_mfma_f32_16x16x32_bf16(A, B0, acc[i][0], 0, 0, 0);
      acc[i][1] = __builtin_amdgcn_mfma_f32_16x16x32_bf16(A, B1, acc[i][1], 0, 0, 0);
    }
  }
#pragma unroll
  for (int i = 0; i < 8; i++) {
    int jb = wave * 128 + i * 16 + quad * 4;
#pragma unroll
    for (int r = 0; r < 4; r++) {
      int j = jb + r;
      float bia = encb[j];
      att1[(size_t)(m0 + lm) * ATT + j]      = f2bf(acc[i][0][r] + bia);
      att1[(size_t)(m0 + 16 + lm) * ATT + j] = f2bf(acc[i][1][r] + bia);
    }
  }
}

// ---------- one-time: ge = xemb @ Wih[:, :512]^T in interleaved gate order ----------
__global__ __launch_bounds__(256) void k_gemb(const u16* __restrict__ Wih_bf,
    const u16* __restrict__ xemb, u16* __restrict__ ge) {
  int tid = threadIdx.x;
  int wave = tid >> 6, lane = tid & 63;
  int m0 = blockIdx.x * 32;
  int jbase = blockIdx.y * 512 + wave * 128;
  int lm = lane & 15, quad = lane >> 4;
  const u16* b0p = xemb + ((size_t)(m0 + lm) << 9) + (quad << 3);
  const u16* b1p = xemb + ((size_t)(m0 + 16 + lm) << 9) + (quad << 3);
  const u16* arow = Wih_bf + (size_t)(jbase + lm) * KX + (quad << 3);
  f32x4 acc[8][2];
#pragma unroll
  for (int i = 0; i < 8; i++) { acc[i][0] = (f32x4){0.f,0.f,0.f,0.f}; acc[i][1] = (f32x4){0.f,0.f,0.f,0.f}; }
  for (int k = 0; k < 512; k += 32) {
    short8 B0 = ld_frag(b0p + k);
    short8 B1 = ld_frag(b1p + k);
#pragma unroll
    for (int i = 0; i < 8; i++) {
      short8 A = ld_frag(arow + (size_t)i * 16 * KX + k);
      acc[i][0] = __builtin_amdgcn_mfma_f32_16x16x32_bf16(A, B0, acc[i][0], 0, 0, 0);
      acc[i][1] = __builtin_amdgcn_mfma_f32_16x16x32_bf16(A, B1, acc[i][1], 0, 0, 0);
    }
  }
#pragma unroll
  for (int i = 0; i < 8; i++) {
#pragma unroll
    for (int r = 0; r < 4; r++) {
      int j = jbase + i * 16 + quad * 4 + r;
      int d = j & 511, g9 = j >> 9;
      int jq = ((d >> 2) << 4) + (g9 << 2) + (d & 3);
      ge[((size_t)(m0 + lm)) * G4 + jq]      = f2bf(acc[i][0][r]);
      ge[((size_t)(m0 + 16 + lm)) * G4 + jq] = f2bf(acc[i][1][r]);
    }
  }
}

// ---------- barrier state init ----------
__global__ __launch_bounds__(256) void k_zero(unsigned* p, int n) {
  int i = blockIdx.x * 256 + threadIdx.x;
  if (i < n) p[i] = 0u;
}

// ---------- single-hop direct-poll device barrier ----------
// arr[NWG] packed dwords. Arrival: relaxed store (preceding __syncthreads
// already drained vmcnt, so payload is at LLC). Every wg's wave 0 polls all
// 256 flags (16 lines) itself -- no leader hop. Bounded spin: ~0.1s bailout
// so a pathological stall surfaces as a wrong answer, not a dead container.
__device__ __forceinline__ void dbar(u32* arr, u32 tag) {
  __syncthreads();
  int tid = threadIdx.x;
  if (tid == 0) {
    __hip_atomic_store(arr + blockIdx.x, tag, __ATOMIC_RELAXED, __HIP_MEMORY_SCOPE_AGENT);
  }
  if (tid < 64) {
    int i0 = tid << 2;
    long sp = 0;
    while (true) {
      u32 a0 = ald_u32(arr + i0);
      u32 a1 = ald_u32(arr + i0 + 1);
      u32 a2 = ald_u32(arr + i0 + 2);
      u32 a3 = ald_u32(arr + i0 + 3);
      bool ok = (a0 >= tag) && (a1 >= tag) && (a2 >= tag) && (a3 >= tag);
      if (__ballot(ok) == ~0ULL) break;
      __builtin_amdgcn_s_sleep(2);
      if (++sp > (1L << 21)) break;   // bounded bailout
    }
  }
  __syncthreads();
}

// ---------- persistent mega-kernel (3 barriers/step) ----------
// P1 [wgs 0-71]:   [att2|gate|hWhh] = h @ W3^T (MFMA, h staged chunk-linear)
// P23 [all 256]:   per b-group of 8: redundant e+softmax, own 256 awe channels
// P4 [wgs 224-255]: gates GEMM (4 awe K-slices staged) + ge + LSTM -> h
__global__ __launch_bounds__(256, 2) void k_mega(
    const int* __restrict__ bxlen,
    const u16* __restrict__ W3,
    const float* __restrict__ decb, const float* __restrict__ fbb,
    const u16* __restrict__ att1, const float* __restrict__ faW, const float* __restrict__ fab,
    const u16* __restrict__ imgsT, const u16* __restrict__ Wih_bf, const u16* __restrict__ ge,
    const float* __restrict__ bih, const float* __restrict__ bhh,
    u16* __restrict__ h_chunk, float* __restrict__ c_glob, u16* __restrict__ h_hist,
    float* __restrict__ att2, float* __restrict__ gatev, float* __restrict__ hWhh,
    u16* __restrict__ x_aweL,
    float* __restrict__ out_alphas,
    u32* __restrict__ bar) {
  const int wg = blockIdx.x;
  const int tid = threadIdx.x;
  const int wid = tid >> 6, lane = tid & 63;
  const int m = lane & 15, quad = lane >> 4;

  __shared__ __align__(16) u16 uSX[16384];      // 32KB staging (P1: h, P4: x slices)
  __shared__ float sG[4][16][33];               // P4 gate exchange
  __shared__ float sA[512], sW[512];
  __shared__ float sAl[PPAD];
  __shared__ float sR[4], sR2[4];

  const float fab0 = fab[0];
  // P23 roles: 8 wgs per b
  const int b_g = wg >> 3, s_g = wg & 7;
  const int len_g = bxlen[b_g];
  // P4 roles
  const int q4 = wg - 224;
  int len4 = 0, b4 = 0, dl4 = 0;
  float c_reg[4] = {0.f, 0.f, 0.f, 0.f};
  if (wg >= 224 && tid < 128) {
    b4 = tid & 31; dl4 = tid >> 5;
    len4 = bxlen[b4];
#pragma unroll
    for (int r = 0; r < 4; r++) c_reg[r] = c_glob[(b4 << 9) + (q4 << 4) + (dl4 << 2) + r];
  }
  for (int i = tid; i < 512; i += 256) sW[i] = faW[i];
  __syncthreads();

  for (int t = 0; t < TT; t++) {
    const u32 base_tag = (u32)t * 3;

    // ---------------- P1: h @ W3^T ----------------
    if (wg < 72) {
      {
        const u32* src = (const u32*)h_chunk;
        u32* dstw = (u32*)uSX;
#pragma unroll
        for (int i = 0; i < 8; i++) {
          int cl = (i << 8) + tid;
          int d4i = cl << 2;
          u32 w0 = ald_u32(src + d4i), w1 = ald_u32(src + d4i + 1);
          u32 w2 = ald_u32(src + d4i + 2), w3 = ald_u32(src + d4i + 3);
          uint4 v = {w0, w1, w2, w3};
          *(uint4*)(dstw + d4i) = v;
        }
      }
      __syncthreads();
      int gw = (wg << 2) + wid;
      int j0 = gw << 4;
      const u16* arow = W3 + ((size_t)(j0 + m) << 9) + (quad << 3);
      f32x4 acc0 = {0.f,0.f,0.f,0.f}, acc1 = {0.f,0.f,0.f,0.f};
#pragma unroll 4
      for (int k = 0; k < 16; k++) {
        short8 a = ld_frag(arow + k * 32);
        short8 x0 = ld_frag(uSX + (((k << 6) + lane) << 3));
        short8 x1 = ld_frag(uSX + 8192 + (((k << 6) + lane) << 3));
        acc0 = __builtin_amdgcn_mfma_f32_16x16x32_bf16(a, x0, acc0, 0, 0, 0);
        acc1 = __builtin_amdgcn_mfma_f32_16x16x32_bf16(a, x1, acc1, 0, 0, 0);
      }
      int jj = j0 + (quad << 2);
      int b0 = m, b1 = 16 + m;
      if (j0 < 512) {
#pragma unroll
        for (int r = 0; r < 4; r++) {
          int j = jj + r; float bia = decb[j];
          ast_f32(&att2[(b0 << 9) + j], acc0[r] + bia);
          ast_f32(&att2[(b1 << 9) + j], acc1[r] + bia);
        }
      } else if (j0 < 2560) {
#pragma unroll
        for (int r = 0; r < 4; r++) {
          int g = jj + r - 512; float bia = fbb[g];
          ast_f32(&gatev[(b0 << 11) + g], sigf(acc0[r] + bia));
          ast_f32(&gatev[(b1 << 11) + g], sigf(acc1[r] + bia));
        }
      } else {
#pragma unroll
        for (int r = 0; r < 4; r++) {
          int j = jj + r - 2560;
          ast_f32(&hWhh[(b0 << 11) + j], acc0[r]);
          ast_f32(&hWhh[(b1 << 11) + j], acc1[r]);
        }
      }
    }
    dbar(bar, base_tag + 1);

    // ---------------- P23: redundant e + softmax + awe (8 wgs/b) ----------------
    if (t < len_g) {
      for (int i = tid; i < 512; i += 256) sA[i] = ald_f32(&att2[(b_g << 9) + i]);
      float gch = ald_f32(&gatev[(b_g << 11) + (s_g << 8) + tid]);
      __syncthreads();
      float e_t = -1e30f;
      if (tid < PP) {
        const uint4* ar = (const uint4*)(att1 + ((size_t)(b_g * PP + tid) << 9));
        float acc = 0.f;
#pragma unroll 8
        for (int k = 0; k < 512; k += 8) {
          float af[8]; unpack8(ar[k >> 3], af);
#pragma unroll
          for (int u = 0; u < 8; u++) {
            float v = af[u] + sA[k + u];
            acc += fmaxf(v, 0.f) * sW[k + u];
          }
        }
        e_t = acc + fab0;
      }
      float wmax = e_t;
#pragma unroll
      for (int off = 32; off; off >>= 1) wmax = fmaxf(wmax, __shfl_xor(wmax, off));
      if (lane == 0) sR[wid] = wmax;
      __syncthreads();
      float mx = fmaxf(fmaxf(sR[0], sR[1]), fmaxf(sR[2], sR[3]));
      float ex = (tid < PP) ? __expf(e_t - mx) : 0.f;
      float wsum = ex;
#pragma unroll
      for (int off = 32; off; off >>= 1) wsum += __shfl_xor(wsum, off);
      if (lane == 0) sR2[wid] = wsum;
      __syncthreads();
      float inv = 1.0f / (sR2[0] + sR2[1] + sR2[2] + sR2[3]);
      float al = ex * inv;
      if (tid < PP) {
        sAl[tid] = al;
        if (s_g == 0) out_alphas[((size_t)b_g * TT + t) * PP + tid] = al;
      } else if (tid < PPAD) {
        sAl[tid] = 0.f;
      }
      __syncthreads();
      int ch = (s_g << 8) + tid;
      const uint4* ip = (const uint4*)(imgsT + ((size_t)(b_g * 2048 + ch)) * PPAD);
      float acc = 0.f;
#pragma unroll
      for (int pg = 0; pg < 26; pg++) {
        uint4 v = ip[pg];
        float f[8]; unpack8(v, f);
#pragma unroll
        for (int u = 0; u < 8; u++) acc += sAl[pg * 8 + u] * f[u];
      }
      ast_u16(&x_aweL[xadr(b_g, ch)], f2bf(gch * acc));
    } else {
      if (s_g == 0 && tid < PP) out_alphas[((size_t)b_g * TT + t) * PP + tid] = 0.f;
    }
    dbar(bar, base_tag + 2);

    // ---------------- P4: gates GEMM (4 awe K-slices) + ge + LSTM ----------------
    if (wg >= 224) {
      f32x4 acc0 = {0.f,0.f,0.f,0.f}, acc1 = {0.f,0.f,0.f,0.f};
      const int row0 = (wid << 9) + (q4 << 4);   // wave = gate, rows d in [16q4,+16)
      for (int s = 0; s < 4; s++) {
        if (s) __syncthreads();
        {
          const u32* src = (const u32*)x_aweL;
#pragma unroll
          for (int i = 0; i < 8; i++) {
            int cl = (i << 8) + tid;
            int plane = cl >> 10, rem = cl & 1023;
            int gi = ((plane << 12) + (s << 10) + rem) << 2;
            u32 w0 = ald_u32(src + gi), w1 = ald_u32(src + gi + 1);
            u32 w2 = ald_u32(src + gi + 2), w3 = ald_u32(src + gi + 3);
            uint4 v = {w0, w1, w2, w3};
            *(uint4*)((u32*)uSX + (cl << 2)) = v;
          }
        }
        __syncthreads();
        const u16* arow = Wih_bf + (size_t)(row0 + m) * KX + 512 + (s << 9) + (quad << 3);
#pragma unroll 4
        for (int k = 0; k < 16; k++) {
          short8 a = ld_frag(arow + k * 32);
          short8 x0 = ld_frag(uSX + (((k << 6) + lane) << 3));
          short8 x1 = ld_frag(uSX + 8192 + (((k << 6) + lane) << 3));
          acc0 = __builtin_amdgcn_mfma_f32_16x16x32_bf16(a, x0, acc0, 0, 0, 0);
          acc1 = __builtin_amdgcn_mfma_f32_16x16x32_bf16(a, x1, acc1, 0, 0, 0);
        }
      }
#pragma unroll
      for (int r = 0; r < 4; r++) {
        int jl = (quad << 2) + r;
        sG[wid][jl][m] = acc0[r];
        sG[wid][jl][16 + m] = acc1[r];
      }
      __syncthreads();
      if (tid < 128 && t < len4) {
        const u16* gep = ge + ((size_t)b4 * TT + t) * G4 + ((((q4 << 2) + dl4)) << 4);
        uint4 gv0 = *(const uint4*)gep;
        uint4 gv1 = *(const uint4*)(gep + 8);
        float gef[16];
        unpack8(gv0, gef);
        unpack8(gv1, gef + 8);
        float pre[4][4];
#pragma unroll
        for (int rr = 0; rr < 4; rr++) {
          int dloc = (dl4 << 2) + rr;
          int d = (q4 << 4) + dloc;
#pragma unroll
          for (int g = 0; g < 4; g++) {
            int j = (g << 9) + d;
            pre[rr][g] = sG[g][dloc][b4] + gef[(g << 2) + rr]
                       + ald_f32(&hWhh[(b4 << 11) + j]) + bih[j] + bhh[j];
          }
        }
#pragma unroll
        for (int rr = 0; rr < 4; rr++) {
          int d = (q4 << 4) + (dl4 << 2) + rr;
          float i_ = sigf(pre[rr][0]);
          float f_ = sigf(pre[rr][1]);
          float g_ = tanhf(pre[rr][2]);
          float o_ = sigf(pre[rr][3]);
          float cn = f_ * c_reg[rr] + i_ * g_;
          float hn = o_ * tanhf(cn);
          c_reg[rr] = cn;
          u16 hb = f2bf(hn);
          ast_u16(&h_chunk[hadr(b4, d)], hb);
          h_hist[((size_t)b4 * TT + t) * DEC + d] = hb;
        }
      }
    }
    dbar(bar, base_tag + 3);
  }
}

// ---------- batched fc ----------
__global__ __launch_bounds__(256) void k_fcall(const int* __restrict__ bxlen,
    const u16* __restrict__ fcW_bf, const float* __restrict__ fcb,
    const u16* __restrict__ h_hist, float* __restrict__ preds) {
  int tid = threadIdx.x;
  int wave = tid >> 6, lane = tid & 63;
  int m0 = blockIdx.x * 32;
  int jbase = blockIdx.y * 512 + wave * 128;
  int lm = lane & 15, quad = lane >> 4;
  const u16* b0p = h_hist + (size_t)(m0 + lm) * DEC + quad * 8;
  const u16* b1p = h_hist + (size_t)(m0 + 16 + lm) * DEC + quad * 8;
  const u16* arow = fcW_bf + (size_t)(jbase + lm) * DEC + quad * 8;
  f32x4 acc[8][2];
#pragma unroll
  for (int i = 0; i < 8; i++) { acc[i][0] = (f32x4){0.f,0.f,0.f,0.f}; acc[i][1] = (f32x4){0.f,0.f,0.f,0.f}; }
  for (int k = 0; k < DEC; k += 32) {
    short8 B0 = ld_frag(b0p + k);
    short8 B1 = ld_frag(b1p + k);
#pragma unroll
    for (int i = 0; i < 8; i++) {
      short8 A = ld_frag(arow + (size_t)i * 16 * DEC + k);
      acc[i][0] = __builtin_amdgcn_mfma_f32_16x16x32_bf16(A, B0, acc[i][0], 0, 0, 0);
      acc[i][1] = __builtin_amdgcn_mfma_f32_16x16x32_bf16(A, B1, acc[i][1], 0, 0, 0);
    }
  }
  int row0 = m0 + lm, row1 = m0 + 16 + lm;
  bool act0 = ((row0 & 127) < bxlen[row0 >> 7]);
  bool act1 = ((row1 & 127) < bxlen[row1 >> 7]);
#pragma unroll
  for (int i = 0; i < 8; i++) {
    int jb = jbase + i * 16 + quad * 4;
#pragma unroll
    for (int r = 0; r < 4; r++) {
      int j = jb + r;
      if (j < VV) {
        float bia = fcb[j];
        preds[(size_t)row0 * VV + j] = act0 ? (acc[i][0][r] + bia) : 0.f;
        preds[(size_t)row1 * VV + j] = act1 ? (acc[i][1][r] + bia) : 0.f;
      }
    }
  }
}

extern "C" void kernel_launch(void* const* d_in, const int* in_sizes, int n_in,
                              void* d_out, int out_size, void* d_ws, size_t ws_size,
                              hipStream_t stream) {
  const float* imgs = (const float*)d_in[0];
  const int* bx     = (const int*)d_in[1];
  const int* bxlen  = (const int*)d_in[2];
  const float* embW = (const float*)d_in[3];
  const float* encW = (const float*)d_in[4];
  const float* encb = (const float*)d_in[5];
  const float* decW = (const float*)d_in[6];
  const float* decb = (const float*)d_in[7];
  const float* faW  = (const float*)d_in[8];
  const float* fab  = (const float*)d_in[9];
  const float* ihW  = (const float*)d_in[10];
  const float* ihb  = (const float*)d_in[11];
  const float* icW  = (const float*)d_in[12];
  const float* icb  = (const float*)d_in[13];
  const float* fbW  = (const float*)d_in[14];
  const float* fbb  = (const float*)d_in[15];
  const float* Wih  = (const float*)d_in[16];
  const float* bih  = (const float*)d_in[17];
  const float* Whh  = (const float*)d_in[18];
  const float* bhh  = (const float*)d_in[19];
  const float* fcW  = (const float*)d_in[20];
  const float* fcb  = (const float*)d_in[21];

  float* out_preds  = (float*)d_out;
  float* out_alphas = out_preds + (size_t)BB * TT * VV;

  char* wsb = (char*)d_ws;
  size_t off = 0;
  // region 0: imgs_bf (setup) ALIASED with imgsT (mega); imgsT written after all imgs_bf readers
  u16* imgs_bf = (u16*)(wsb + off);
  u16* imgsT   = (u16*)(wsb + off);
  off += (size_t)BB * 2048 * PPAD * 2;                                  // 27.26 MB
  u16* W3_bf   = (u16*)(wsb + off); off += (size_t)4608 * DEC * 2;      // 4.72 MB
  u16* Wih_bf  = (u16*)(wsb + off); off += (size_t)G4 * KX * 2;         // 10.49 MB
  u16* fcW_bf  = (u16*)(wsb + off); off += (size_t)VVP * DEC * 2;       // 10.49 MB
  u16* encW_bf = (u16*)(wsb + off); off += (size_t)ATT * ENC * 2;       // 2.00 MB
  u16* att1    = (u16*)(wsb + off);
  u16* W2_bf   = att1;                      // aliased (consumed before att1 write)
  u16* mean_bf = att1 + (size_t)1024 * ENC;
  off += (size_t)BB * PP * ATT * 2;                                     // 6.42 MB
  u16* xemb    = (u16*)(wsb + off); off += (size_t)BB * TT * EMB * 2;   // 4.19 MB
  u16* h_hist  = (u16*)(wsb + off); off += (size_t)BB * TT * DEC * 2;   // 4.19 MB
  u16* ge      = (u16*)(wsb + off); off += (size_t)BB * TT * G4 * 2;    // 16.78 MB
  u16* h_chunk = (u16*)(wsb + off); off += (size_t)BB * DEC * 2;
  float* c      = (float*)(wsb + off); off += (size_t)BB * DEC * 4;
  float* att2   = (float*)(wsb + off); off += (size_t)BB * ATT * 4;
  float* gatev  = (float*)(wsb + off); off += (size_t)BB * ENC * 4;
  float* hWhh   = (float*)(wsb + off); off += (size_t)BB * G4 * 4;
  u16* x_aweL   = (u16*)(wsb + off); off += (size_t)BB * ENC * 2;
  u32* bar      = (u32*)(wsb + off); off += (size_t)512 * 4;

  // one-time conversions + hoists
  k_cvt<<<(BB * PP * ENC) / 2048, 256, 0, stream>>>(imgs, imgs_bf, BB * PP * ENC);
  k_cvt<<<(DEC * DEC) / 2048, 256, 0, stream>>>(decW, W3_bf, DEC * DEC);
  k_cvt<<<(ENC * DEC) / 2048, 256, 0, stream>>>(fbW, W3_bf + (size_t)DEC * DEC, ENC * DEC);
  k_cvt<<<(G4 * DEC) / 2048, 256, 0, stream>>>(Whh, W3_bf + (size_t)(DEC + ENC) * DEC, G4 * DEC);
  k_cvt<<<(G4 * KX) / 2048, 256, 0, stream>>>(Wih, Wih_bf, G4 * KX);
  k_cvt<<<(VV * DEC) / 2048, 256, 0, stream>>>(fcW, fcW_bf, VV * DEC);
  k_cvt<<<(ATT * ENC) / 2048, 256, 0, stream>>>(encW, encW_bf, ATT * ENC);
  k_cvt<<<(DEC * ENC) / 2048, 256, 0, stream>>>(ihW, W2_bf, DEC * ENC);
  k_cvt<<<(DEC * ENC) / 2048, 256, 0, stream>>>(icW, W2_bf + (size_t)DEC * ENC, DEC * ENC);
  k_emball<<<(BB * TT * EMB / 8) / 256, 256, 0, stream>>>(bx, embW, xemb);
  k_gemb<<<dim3((BB * TT) / 32, 4), 256, 0, stream>>>(Wih_bf, xemb, ge);

  k_mean<<<BB * 4, 256, 0, stream>>>(imgs_bf, mean_bf);
  k_init2<<<64, 64, 0, stream>>>(W2_bf, ihb, icb, mean_bf, h_chunk, c);
  k_att1<<<(BB * PP) / 32, 256, 0, stream>>>(imgs_bf, encW_bf, encb, att1);
  // transpose AFTER all imgs_bf readers (overwrites aliased region)
  k_timg<<<32 * 256, 256, 0, stream>>>(imgs, imgsT);
  k_zero<<<2, 256, 0, stream>>>(bar, 512);

  // persistent recurrence
  k_mega<<<NWG, 256, 0, stream>>>(bxlen, W3_bf, decb, fbb, att1, faW, fab,
                                  imgsT, Wih_bf, ge, bih, bhh,
                                  h_chunk, c, h_hist, att2, gatev, hWhh,
                                  x_aweL, out_alphas, bar);

  // batched fc over all (b,t)
  k_fcall<<<dim3((BB * TT) / 32, 20), 256, 0, stream>>>(bxlen, fcW_bf, fcb, h_hist, out_preds);
}

// Round 6
// 8396.062 us; speedup vs baseline: 1.3517x; 1.3517x over previous
//
#include <hip/hip_runtime.h>
#include <hip/hip_bf16.h>

#define BB 32
#define TT 128
#define PP 196
#define PPAD 208
#define ENC 2048
#define DEC 512
#define ATT 512
#define EMB 512
#define VV 10000
#define VVP 10240
#define G4 2048
#define KX 2560
#define NWG 256

typedef unsigned short u16;
typedef unsigned int u32;
typedef __attribute__((ext_vector_type(8))) short short8;
typedef __attribute__((ext_vector_type(4))) float f32x4;

__device__ __forceinline__ float bf2f(u16 u) { return __uint_as_float(((u32)u) << 16); }
__device__ __forceinline__ u16 f2bf(float f) {
  u32 x = __float_as_uint(f);
  u32 r = (x + 0x7fffu + ((x >> 16) & 1u)) >> 16;
  return (u16)r;
}
__device__ __forceinline__ void unpack8(uint4 v, float* f) {
  f[0] = __uint_as_float(v.x << 16); f[1] = __uint_as_float(v.x & 0xffff0000u);
  f[2] = __uint_as_float(v.y << 16); f[3] = __uint_as_float(v.y & 0xffff0000u);
  f[4] = __uint_as_float(v.z << 16); f[5] = __uint_as_float(v.z & 0xffff0000u);
  f[6] = __uint_as_float(v.w << 16); f[7] = __uint_as_float(v.w & 0xffff0000u);
}
__device__ __forceinline__ void load8(const float* __restrict__ p, float* f) {
  float4 a = ((const float4*)p)[0];
  float4 b = ((const float4*)p)[1];
  f[0] = a.x; f[1] = a.y; f[2] = a.z; f[3] = a.w;
  f[4] = b.x; f[5] = b.y; f[6] = b.z; f[7] = b.w;
}
__device__ __forceinline__ float sigf(float x) { return 1.0f / (1.0f + __expf(-x)); }
__device__ __forceinline__ short8 ld_frag(const u16* __restrict__ p) {
  union { uint4 u; short8 s; } cv;
  cv.u = *(const uint4*)p;
  return cv.s;
}

// ---- device-scope relaxed atomics (LLC-coherent, bypass non-coherent L2) ----
__device__ __forceinline__ void ast_f32(float* p, float v) {
  __hip_atomic_store(p, v, __ATOMIC_RELAXED, __HIP_MEMORY_SCOPE_AGENT);
}
__device__ __forceinline__ float ald_f32(const float* p) {
  return __hip_atomic_load((float*)p, __ATOMIC_RELAXED, __HIP_MEMORY_SCOPE_AGENT);
}
__device__ __forceinline__ u32 ald_u32(const u32* p) {
  return __hip_atomic_load((u32*)p, __ATOMIC_RELAXED, __HIP_MEMORY_SCOPE_AGENT);
}
__device__ __forceinline__ void ast_u32(u32* p, u32 v) {
  __hip_atomic_store(p, v, __ATOMIC_RELAXED, __HIP_MEMORY_SCOPE_AGENT);
}
__device__ __forceinline__ void ast_u16(u16* p, u16 v) {
  __hip_atomic_store(p, v, __ATOMIC_RELAXED, __HIP_MEMORY_SCOPE_AGENT);
}
__device__ __forceinline__ void wait_ge(u32* p, u32 tag) {
  long sp = 0;
  while (ald_u32(p) < tag) {
    __builtin_amdgcn_s_sleep(2);
    if (++sp > (1L << 21)) break;   // bounded bailout
  }
}

// chunk-linear addressing (chunk = one lane's ds_read_b128 payload)
__device__ __forceinline__ int hadr(int b, int d) {
  return ((((b >> 4) << 10) + ((d >> 5) << 6) + (((d >> 3) & 3) << 4) + (b & 15)) << 3) + (d & 7);
}
__device__ __forceinline__ int xadr(int b, int ch) {
  return ((((b >> 4) << 12) + ((ch >> 5) << 6) + (((ch >> 3) & 3) << 4) + (b & 15)) << 3) + (ch & 7);
}

// flag offsets in the bar array (dwords; per-flag stride 32 dwords = 128B)
#define F_P1   0        // 72 flags
#define F_XD   4096     // 256 flags
#define F_PART 16384    // 32 flags
#define F_HD   18432    // 32 flags
#define F_G1   20480    // 8 replicas
#define F_G3   21504    // 8 replicas

// ---------- one-time f32 -> bf16 conversion ----------
__global__ __launch_bounds__(256) void k_cvt(const float* __restrict__ src, u16* __restrict__ dst, int n) {
  int i0 = (blockIdx.x * 256 + threadIdx.x) * 8;
  if (i0 >= n) return;
  float f[8]; load8(src + i0, f);
  u16 o[8];
#pragma unroll
  for (int u = 0; u < 8; u++) o[u] = f2bf(f[u]);
  *(uint4*)(dst + i0) = *(const uint4*)o;
}

// ---------- one-time: gather emb rows -> xemb bf16 (4096 x 512) ----------
__global__ __launch_bounds__(256) void k_emball(const int* __restrict__ bx,
    const float* __restrict__ embW, u16* __restrict__ xemb) {
  int flat = blockIdx.x * 256 + threadIdx.x;
  int row = flat >> 6;
  int c8 = (flat & 63) * 8;
  int tok = bx[row];
  const float* e = embW + (size_t)tok * EMB + c8;
  float f[8]; load8(e, f);
  u16 o[8];
#pragma unroll
  for (int u = 0; u < 8; u++) o[u] = f2bf(f[u]);
  *(uint4*)(xemb + (size_t)row * EMB + c8) = *(const uint4*)o;
}

// ---------- one-time: transpose imgs f32 -> imgsT bf16 [b][ch][p(pad 208)] ----------
__global__ __launch_bounds__(256) void k_timg(const float* __restrict__ imgs, u16* __restrict__ imgsT) {
  int b = blockIdx.x >> 8;
  int sub = blockIdx.x & 255;
  int flat = sub * 256 + threadIdx.x;
  int ch = flat >> 5, pg = flat & 31;
  if (pg >= 26) return;
  u16 o[8];
#pragma unroll
  for (int j = 0; j < 8; j++) {
    int p = pg * 8 + j;
    float v = (p < PP) ? imgs[((size_t)b * PP + p) * ENC + ch] : 0.f;
    o[j] = f2bf(v);
  }
  *(uint4*)(imgsT + ((size_t)b * 2048 + ch) * PPAD + pg * 8) = *(const uint4*)o;
}

// ---------- mean over p ----------
__global__ __launch_bounds__(256) void k_mean(const u16* __restrict__ imgs_bf, u16* __restrict__ mean_bf) {
  int b = blockIdx.x >> 2, chunk = blockIdx.x & 3;
  int ch0 = chunk * 512 + threadIdx.x * 2;
  const u32* base = (const u32*)(imgs_bf + (size_t)b * PP * ENC + ch0);
  float a0 = 0.f, a1 = 0.f;
#pragma unroll 4
  for (int p = 0; p < PP; p++) {
    u32 u = base[(size_t)p * (ENC / 2)];
    a0 += __uint_as_float(u << 16);
    a1 += __uint_as_float(u & 0xffff0000u);
  }
  const float inv = 1.0f / PP;
  u16 o[2] = { f2bf(a0 * inv), f2bf(a1 * inv) };
  *(u32*)(mean_bf + b * ENC + ch0) = *(const u32*)o;
}

// ---------- init via MFMA: h0 (chunk layout) and c0 ----------
__global__ __launch_bounds__(64) void k_init2(const u16* __restrict__ W2_bf,
    const float* __restrict__ ihb, const float* __restrict__ icb,
    const u16* __restrict__ mean_bf, u16* __restrict__ h_chunk, float* __restrict__ c) {
  int lane = threadIdx.x;
  int j0 = blockIdx.x * 16;
  int m = lane & 15, quad = lane >> 4;
  const u16* arow = W2_bf + (size_t)(j0 + m) * ENC + quad * 8;
  const u16* xb0 = mean_bf + (size_t)m * ENC + quad * 8;
  const u16* xb1 = mean_bf + (size_t)(16 + m) * ENC + quad * 8;
  f32x4 acc0 = {0.f,0.f,0.f,0.f}, acc1 = {0.f,0.f,0.f,0.f};
  for (int k = 0; k < ENC; k += 32) {
    short8 a = ld_frag(arow + k);
    short8 x0 = ld_frag(xb0 + k);
    short8 x1 = ld_frag(xb1 + k);
    acc0 = __builtin_amdgcn_mfma_f32_16x16x32_bf16(a, x0, acc0, 0, 0, 0);
    acc1 = __builtin_amdgcn_mfma_f32_16x16x32_bf16(a, x1, acc1, 0, 0, 0);
  }
  int jj = j0 + quad * 4;
  int b0 = m, b1 = 16 + m;
#pragma unroll
  for (int r = 0; r < 4; r++) {
    int j = jj + r;
    if (j < 512) {
      float bia = ihb[j];
      h_chunk[hadr(b0, j)] = f2bf(acc0[r] + bia);
      h_chunk[hadr(b1, j)] = f2bf(acc1[r] + bia);
    } else {
      int g = j - 512;
      float bia = icb[g];
      c[b0 * DEC + g] = acc0[r] + bia;
      c[b1 * DEC + g] = acc1[r] + bia;
    }
  }
}

// ---------- att1 via MFMA ----------
__global__ __launch_bounds__(256) void k_att1(const u16* __restrict__ imgs_bf,
    const u16* __restrict__ encW_bf, const float* __restrict__ encb, u16* __restrict__ att1) {
  int tid = threadIdx.x;
  int wave = tid >> 6, lane = tid & 63;
  int m0 = blockIdx.x * 32;
  int lm = lane & 15, quad = lane >> 4;
  const u16* b0p = imgs_bf + (size_t)(m0 + lm) * ENC + quad * 8;
  const u16* b1p = imgs_bf + (size_t)(m0 + 16 + lm) * ENC + quad * 8;
  const u16* arow = encW_bf + (size_t)(wave * 128 + lm) * ENC + quad * 8;
  f32x4 acc[8][2];
#pragma unroll
  for (int i = 0; i < 8; i++) { acc[i][0] = (f32x4){0.f,0.f,0.f,0.f}; acc[i][1] = (f32x4){0.f,0.f,0.f,0.f}; }
  for (int k = 0; k < ENC; k += 32) {
    short8 B0 = ld_frag(b0p + k);
    short8 B1 = ld_frag(b1p + k);
#pragma unroll
    for (int i = 0; i < 8; i++) {
      short8 A = ld_frag(arow + (size_t)i * 16 * ENC + k);
      acc[i][0] = __builtin_amdgcn_mfma_f32_16x16x32_bf16(A, B0, acc[i][0], 0, 0, 0);
      acc[i][1] = __builtin_amdgcn_mfma_f32_16x16x32_bf16(A, B1, acc[i][1], 0, 0, 0);
    }
  }
#pragma unroll
  for (int i = 0; i < 8; i++) {
    int jb = wave * 128 + i * 16 + quad * 4;
#pragma unroll
    for (int r = 0; r < 4; r++) {
      int j = jb + r;
      float bia = encb[j];
      att1[(size_t)(m0 + lm) * ATT + j]      = f2bf(acc[i][0][r] + bia);
      att1[(size_t)(m0 + 16 + lm) * ATT + j] = f2bf(acc[i][1][r] + bia);
    }
  }
}

// ---------- one-time: ge = xemb @ Wih[:, :512]^T in interleaved gate order ----------
__global__ __launch_bounds__(256) void k_gemb(const u16* __restrict__ Wih_bf,
    const u16* __restrict__ xemb, u16* __restrict__ ge) {
  int tid = threadIdx.x;
  int wave = tid >> 6, lane = tid & 63;
  int m0 = blockIdx.x * 32;
  int jbase = blockIdx.y * 512 + wave * 128;
  int lm = lane & 15, quad = lane >> 4;
  const u16* b0p = xemb + ((size_t)(m0 + lm) << 9) + (quad << 3);
  const u16* b1p = xemb + ((size_t)(m0 + 16 + lm) << 9) + (quad << 3);
  const u16* arow = Wih_bf + (size_t)(jbase + lm) * KX + (quad << 3);
  f32x4 acc[8][2];
#pragma unroll
  for (int i = 0; i < 8; i++) { acc[i][0] = (f32x4){0.f,0.f,0.f,0.f}; acc[i][1] = (f32x4){0.f,0.f,0.f,0.f}; }
  for (int k = 0; k < 512; k += 32) {
    short8 B0 = ld_frag(b0p + k);
    short8 B1 = ld_frag(b1p + k);
#pragma unroll
    for (int i = 0; i < 8; i++) {
      short8 A = ld_frag(arow + (size_t)i * 16 * KX + k);
      acc[i][0] = __builtin_amdgcn_mfma_f32_16x16x32_bf16(A, B0, acc[i][0], 0, 0, 0);
      acc[i][1] = __builtin_amdgcn_mfma_f32_16x16x32_bf16(A, B1, acc[i][1], 0, 0, 0);
    }
  }
#pragma unroll
  for (int i = 0; i < 8; i++) {
#pragma unroll
    for (int r = 0; r < 4; r++) {
      int j = jbase + i * 16 + quad * 4 + r;
      int d = j & 511, g9 = j >> 9;
      int jq = ((d >> 2) << 4) + (g9 << 2) + (d & 3);
      ge[((size_t)(m0 + lm)) * G4 + jq]      = f2bf(acc[i][0][r]);
      ge[((size_t)(m0 + 16 + lm)) * G4 + jq] = f2bf(acc[i][1][r]);
    }
  }
}

// ---------- barrier state init ----------
__global__ __launch_bounds__(256) void k_zero(unsigned* p, int n) {
  int i = blockIdx.x * 256 + threadIdx.x;
  if (i < n) p[i] = 0u;
}

// ---------- persistent mega-kernel: flag-based pipeline, 1 wg/CU ----------
// wgs 0-71:  P1 (wait gen3) -> flag p1d; then P23 -> flag xd
// wgs 72-223: P23 (wait gen1) -> flag xd
// wgs 224-255: P23 -> flag xd -> mini-bar2 -> P4 -> flag hd
// wg255 additionally: gen1 leader (idle in P1). wg0: gen3 leader (idle in P4).
__global__ __launch_bounds__(256, 1) void k_mega(
    const int* __restrict__ bxlen,
    const u16* __restrict__ W3,
    const float* __restrict__ decb, const float* __restrict__ fbb,
    const u16* __restrict__ att1, const float* __restrict__ faW, const float* __restrict__ fab,
    const u16* __restrict__ imgsT, const u16* __restrict__ Wih_bf, const u16* __restrict__ ge,
    const float* __restrict__ bih, const float* __restrict__ bhh,
    u16* __restrict__ h_chunk, float* __restrict__ c_glob, u16* __restrict__ h_hist,
    float* __restrict__ att2, float* __restrict__ gatev, float* __restrict__ hWhh,
    u16* __restrict__ x_aweL,
    float* __restrict__ out_alphas,
    u32* __restrict__ bar) {
  const int wg = blockIdx.x;
  const int tid = threadIdx.x;
  const int wid = tid >> 6, lane = tid & 63;
  const int m = lane & 15, quad = lane >> 4;
  const bool isP1 = (wg < 72);
  const bool isP4 = (wg >= 224);
  const int q4 = wg - 224;

  __shared__ __align__(16) u16 uSX[65536];      // 128KB: P1 stages h (32KB), P4 stages x_awe (128KB)
  __shared__ float sG[4][16][33];
  __shared__ float sA[512], sW[512];
  __shared__ float sAl[PPAD];
  __shared__ float sR[4], sR2[4];

  const float fab0 = fab[0];
  const int b_g = wg >> 3, s_g = wg & 7;
  const int len_g = bxlen[b_g];
  int len4 = 0, b4 = 0, dl4 = 0;
  float c_reg[4] = {0.f, 0.f, 0.f, 0.f};
  if (isP4 && tid < 128) {
    b4 = tid & 31; dl4 = tid >> 5;
    len4 = bxlen[b4];
#pragma unroll
    for (int r = 0; r < 4; r++) c_reg[r] = c_glob[(b4 << 9) + (q4 << 4) + (dl4 << 2) + r];
  }
  for (int i = tid; i < 512; i += 256) sW[i] = faW[i];
  __syncthreads();

  for (int t = 0; t < TT; t++) {
    const u32 tag = (u32)(t + 1);

    // ================= P1 (wgs 0-71) =================
    if (isP1) {
      if (t > 0 && wg != 0) {
        if (tid == 0) wait_ge(bar + F_G3 + (wg & 7) * 32, (u32)t);
        __syncthreads();
      }
      // stage h (chunk-linear, atomic dwords)
      {
        const u32* src = (const u32*)h_chunk;
        u32* dstw = (u32*)uSX;
#pragma unroll
        for (int i = 0; i < 8; i++) {
          int d4i = ((i << 8) + tid) << 2;
          u32 w0 = ald_u32(src + d4i), w1 = ald_u32(src + d4i + 1);
          u32 w2 = ald_u32(src + d4i + 2), w3 = ald_u32(src + d4i + 3);
          uint4 v = {w0, w1, w2, w3};
          *(uint4*)(dstw + d4i) = v;
        }
      }
      __syncthreads();
      int gw = (wg << 2) + wid;
      int j0 = gw << 4;
      const u16* arow = W3 + ((size_t)(j0 + m) << 9) + (quad << 3);
      f32x4 acc0 = {0.f,0.f,0.f,0.f}, acc1 = {0.f,0.f,0.f,0.f};
#pragma unroll 4
      for (int k = 0; k < 16; k++) {
        short8 a = ld_frag(arow + k * 32);
        short8 x0 = ld_frag(uSX + (((k << 6) + lane) << 3));
        short8 x1 = ld_frag(uSX + 8192 + (((k << 6) + lane) << 3));
        acc0 = __builtin_amdgcn_mfma_f32_16x16x32_bf16(a, x0, acc0, 0, 0, 0);
        acc1 = __builtin_amdgcn_mfma_f32_16x16x32_bf16(a, x1, acc1, 0, 0, 0);
      }
      int jj = j0 + (quad << 2);
      int b0 = m, b1 = 16 + m;
      if (j0 < 512) {
#pragma unroll
        for (int r = 0; r < 4; r++) {
          int j = jj + r; float bia = decb[j];
          ast_f32(&att2[(b0 << 9) + j], acc0[r] + bia);
          ast_f32(&att2[(b1 << 9) + j], acc1[r] + bia);
        }
      } else if (j0 < 2560) {
#pragma unroll
        for (int r = 0; r < 4; r++) {
          int g = jj + r - 512; float bia = fbb[g];
          ast_f32(&gatev[(b0 << 11) + g], sigf(acc0[r] + bia));
          ast_f32(&gatev[(b1 << 11) + g], sigf(acc1[r] + bia));
        }
      } else {
#pragma unroll
        for (int r = 0; r < 4; r++) {
          int j = jj + r - 2560;
          ast_f32(&hWhh[(b0 << 11) + j], acc0[r]);
          ast_f32(&hWhh[(b1 << 11) + j], acc1[r]);
        }
      }
      __syncthreads();                       // drain stores (vmcnt) before flag
      if (tid == 0) ast_u32(bar + F_P1 + wg * 32, tag);
    }

    // ================= gen1: P1 done =================
    if (wg == 255) {
      if (wid == 0) {
        long sp = 0;
        while (true) {
          u32 a = ald_u32(bar + F_P1 + lane * 32);                      // flags 0-63
          u32 b2 = (lane < 8) ? ald_u32(bar + F_P1 + (lane + 64) * 32) : 0xffffffffu;
          bool ok = (a >= tag) && (b2 >= tag);
          if (__ballot(ok) == ~0ULL) break;
          __builtin_amdgcn_s_sleep(2);
          if (++sp > (1L << 21)) break;
        }
        if (lane == 0)
          for (int r2 = 0; r2 < 8; r2++) ast_u32(bar + F_G1 + r2 * 32, tag);
      }
      __syncthreads();
    } else {
      if (tid == 0) wait_ge(bar + F_G1 + (wg & 7) * 32, tag);
      __syncthreads();
    }

    // ================= P23: e + softmax + awe (all wgs, 8/b) =================
    if (t < len_g) {
      for (int i = tid; i < 512; i += 256) sA[i] = ald_f32(&att2[(b_g << 9) + i]);
      float gch = ald_f32(&gatev[(b_g << 11) + (s_g << 8) + tid]);
      __syncthreads();
      float e_t = -1e30f;
      if (tid < PP) {
        const uint4* ar = (const uint4*)(att1 + ((size_t)(b_g * PP + tid) << 9));
        float acc = 0.f;
#pragma unroll 8
        for (int k = 0; k < 512; k += 8) {
          float af[8]; unpack8(ar[k >> 3], af);
#pragma unroll
          for (int u = 0; u < 8; u++) {
            float v = af[u] + sA[k + u];
            acc += fmaxf(v, 0.f) * sW[k + u];
          }
        }
        e_t = acc + fab0;
      }
      float wmax = e_t;
#pragma unroll
      for (int off = 32; off; off >>= 1) wmax = fmaxf(wmax, __shfl_xor(wmax, off));
      if (lane == 0) sR[wid] = wmax;
      __syncthreads();
      float mx = fmaxf(fmaxf(sR[0], sR[1]), fmaxf(sR[2], sR[3]));
      float ex = (tid < PP) ? __expf(e_t - mx) : 0.f;
      float wsum = ex;
#pragma unroll
      for (int off = 32; off; off >>= 1) wsum += __shfl_xor(wsum, off);
      if (lane == 0) sR2[wid] = wsum;
      __syncthreads();
      float inv = 1.0f / (sR2[0] + sR2[1] + sR2[2] + sR2[3]);
      float al = ex * inv;
      if (tid < PP) {
        sAl[tid] = al;
        if (s_g == 0) out_alphas[((size_t)b_g * TT + t) * PP + tid] = al;
      } else if (tid < PPAD) {
        sAl[tid] = 0.f;
      }
      __syncthreads();
      int ch = (s_g << 8) + tid;
      const uint4* ip = (const uint4*)(imgsT + ((size_t)(b_g * 2048 + ch)) * PPAD);
      float acc = 0.f;
#pragma unroll
      for (int pg = 0; pg < 26; pg++) {
        uint4 v = ip[pg];
        float f[8]; unpack8(v, f);
#pragma unroll
        for (int u = 0; u < 8; u++) acc += sAl[pg * 8 + u] * f[u];
      }
      ast_u16(&x_aweL[xadr(b_g, ch)], f2bf(gch * acc));
    } else {
      if (s_g == 0 && tid < PP) out_alphas[((size_t)b_g * TT + t) * PP + tid] = 0.f;
    }
    __syncthreads();                       // drain x_awe stores before flag
    if (tid == 0) ast_u32(bar + F_XD + wg * 32, tag);

    // ================= P4 (wgs 224-255): mini-bar2 + gates GEMM + LSTM =================
    if (isP4) {
      if (wid == 0) {
        long sp = 0;
        while (true) {                    // my 8-wg slice of xd
          bool ok = true;
          if (lane < 8) ok = ald_u32(bar + F_XD + (q4 * 8 + lane) * 32) >= tag;
          if (__ballot(ok) == ~0ULL) break;
          __builtin_amdgcn_s_sleep(2);
          if (++sp > (1L << 21)) break;
        }
        if (lane == 0) ast_u32(bar + F_PART + q4 * 32, tag);
        sp = 0;
        while (true) {                    // all 32 parts
          bool ok = true;
          if (lane < 32) ok = ald_u32(bar + F_PART + lane * 32) >= tag;
          if (__ballot(ok) == ~0ULL) break;
          __builtin_amdgcn_s_sleep(2);
          if (++sp > (1L << 21)) break;
        }
      }
      __syncthreads();
      // stage full x_awe (128KB) chunk-linear -> LDS linear
      {
        const u32* src = (const u32*)x_aweL;
        u32* dstw = (u32*)uSX;
#pragma unroll 8
        for (int i = 0; i < 32; i++) {
          int d4i = ((i << 8) + tid) << 2;
          u32 w0 = ald_u32(src + d4i), w1 = ald_u32(src + d4i + 1);
          u32 w2 = ald_u32(src + d4i + 2), w3 = ald_u32(src + d4i + 3);
          uint4 v = {w0, w1, w2, w3};
          *(uint4*)(dstw + d4i) = v;
        }
      }
      __syncthreads();
      f32x4 acc0 = {0.f,0.f,0.f,0.f}, acc1 = {0.f,0.f,0.f,0.f};
      const int row0 = (wid << 9) + (q4 << 4);
      const u16* arow = Wih_bf + (size_t)(row0 + m) * KX + 512 + (quad << 3);
#pragma unroll 4
      for (int k = 0; k < 64; k++) {
        short8 a = ld_frag(arow + (k << 5));
        short8 x0 = ld_frag(uSX + (((k << 6) + lane) << 3));
        short8 x1 = ld_frag(uSX + 32768 + (((k << 6) + lane) << 3));
        acc0 = __builtin_amdgcn_mfma_f32_16x16x32_bf16(a, x0, acc0, 0, 0, 0);
        acc1 = __builtin_amdgcn_mfma_f32_16x16x32_bf16(a, x1, acc1, 0, 0, 0);
      }
#pragma unroll
      for (int r = 0; r < 4; r++) {
        int jl = (quad << 2) + r;
        sG[wid][jl][m] = acc0[r];
        sG[wid][jl][16 + m] = acc1[r];
      }
      __syncthreads();
      if (tid < 128 && t < len4) {
        const u16* gep = ge + ((size_t)b4 * TT + t) * G4 + ((((q4 << 2) + dl4)) << 4);
        uint4 gv0 = *(const uint4*)gep;
        uint4 gv1 = *(const uint4*)(gep + 8);
        float gef[16];
        unpack8(gv0, gef);
        unpack8(gv1, gef + 8);
        float pre[4][4];
#pragma unroll
        for (int rr = 0; rr < 4; rr++) {
          int dloc = (dl4 << 2) + rr;
          int d = (q4 << 4) + dloc;
#pragma unroll
          for (int g = 0; g < 4; g++) {
            int j = (g << 9) + d;
            pre[rr][g] = sG[g][dloc][b4] + gef[(g << 2) + rr]
                       + ald_f32(&hWhh[(b4 << 11) + j]) + bih[j] + bhh[j];
          }
        }
#pragma unroll
        for (int rr = 0; rr < 4; rr++) {
          int d = (q4 << 4) + (dl4 << 2) + rr;
          float i_ = sigf(pre[rr][0]);
          float f_ = sigf(pre[rr][1]);
          float g_ = tanhf(pre[rr][2]);
          float o_ = sigf(pre[rr][3]);
          float cn = f_ * c_reg[rr] + i_ * g_;
          float hn = o_ * tanhf(cn);
          c_reg[rr] = cn;
          u16 hb = f2bf(hn);
          ast_u16(&h_chunk[hadr(b4, d)], hb);
          h_hist[((size_t)b4 * TT + t) * DEC + d] = hb;
        }
      }
      __syncthreads();                     // drain h stores before flag
      if (tid == 0) ast_u32(bar + F_HD + q4 * 32, tag);
    }

    // ================= gen3: h done (leader wg0, idle during P4) =================
    if (wg == 0) {
      if (wid == 0) {
        long sp = 0;
        while (true) {
          bool ok = true;
          if (lane < 32) ok = ald_u32(bar + F_HD + lane * 32) >= tag;
          if (__ballot(ok) == ~0ULL) break;
          __builtin_amdgcn_s_sleep(2);
          if (++sp > (1L << 21)) break;
        }
        if (lane == 0)
          for (int r2 = 0; r2 < 8; r2++) ast_u32(bar + F_G3 + r2 * 32, tag);
      }
      __syncthreads();
    }
  }
}

// ---------- batched fc ----------
__global__ __launch_bounds__(256) void k_fcall(const int* __restrict__ bxlen,
    const u16* __restrict__ fcW_bf, const float* __restrict__ fcb,
    const u16* __restrict__ h_hist, float* __restrict__ preds) {
  int tid = threadIdx.x;
  int wave = tid >> 6, lane = tid & 63;
  int m0 = blockIdx.x * 32;
  int jbase = blockIdx.y * 512 + wave * 128;
  int lm = lane & 15, quad = lane >> 4;
  const u16* b0p = h_hist + (size_t)(m0 + lm) * DEC + quad * 8;
  const u16* b1p = h_hist + (size_t)(m0 + 16 + lm) * DEC + quad * 8;
  const u16* arow = fcW_bf + (size_t)(jbase + lm) * DEC + quad * 8;
  f32x4 acc[8][2];
#pragma unroll
  for (int i = 0; i < 8; i++) { acc[i][0] = (f32x4){0.f,0.f,0.f,0.f}; acc[i][1] = (f32x4){0.f,0.f,0.f,0.f}; }
  for (int k = 0; k < DEC; k += 32) {
    short8 B0 = ld_frag(b0p + k);
    short8 B1 = ld_frag(b1p + k);
#pragma unroll
    for (int i = 0; i < 8; i++) {
      short8 A = ld_frag(arow + (size_t)i * 16 * DEC + k);
      acc[i][0] = __builtin_amdgcn_mfma_f32_16x16x32_bf16(A, B0, acc[i][0], 0, 0, 0);
      acc[i][1] = __builtin_amdgcn_mfma_f32_16x16x32_bf16(A, B1, acc[i][1], 0, 0, 0);
    }
  }
  int row0 = m0 + lm, row1 = m0 + 16 + lm;
  bool act0 = ((row0 & 127) < bxlen[row0 >> 7]);
  bool act1 = ((row1 & 127) < bxlen[row1 >> 7]);
#pragma unroll
  for (int i = 0; i < 8; i++) {
    int jb = jbase + i * 16 + quad * 4;
#pragma unroll
    for (int r = 0; r < 4; r++) {
      int j = jb + r;
      if (j < VV) {
        float bia = fcb[j];
        preds[(size_t)row0 * VV + j] = act0 ? (acc[i][0][r] + bia) : 0.f;
        preds[(size_t)row1 * VV + j] = act1 ? (acc[i][1][r] + bia) : 0.f;
      }
    }
  }
}

extern "C" void kernel_launch(void* const* d_in, const int* in_sizes, int n_in,
                              void* d_out, int out_size, void* d_ws, size_t ws_size,
                              hipStream_t stream) {
  const float* imgs = (const float*)d_in[0];
  const int* bx     = (const int*)d_in[1];
  const int* bxlen  = (const int*)d_in[2];
  const float* embW = (const float*)d_in[3];
  const float* encW = (const float*)d_in[4];
  const float* encb = (const float*)d_in[5];
  const float* decW = (const float*)d_in[6];
  const float* decb = (const float*)d_in[7];
  const float* faW  = (const float*)d_in[8];
  const float* fab  = (const float*)d_in[9];
  const float* ihW  = (const float*)d_in[10];
  const float* ihb  = (const float*)d_in[11];
  const float* icW  = (const float*)d_in[12];
  const float* icb  = (const float*)d_in[13];
  const float* fbW  = (const float*)d_in[14];
  const float* fbb  = (const float*)d_in[15];
  const float* Wih  = (const float*)d_in[16];
  const float* bih  = (const float*)d_in[17];
  const float* Whh  = (const float*)d_in[18];
  const float* bhh  = (const float*)d_in[19];
  const float* fcW  = (const float*)d_in[20];
  const float* fcb  = (const float*)d_in[21];

  float* out_preds  = (float*)d_out;
  float* out_alphas = out_preds + (size_t)BB * TT * VV;

  char* wsb = (char*)d_ws;
  size_t off = 0;
  // region 0: imgs_bf (setup) ALIASED with imgsT (mega); imgsT written after all imgs_bf readers
  u16* imgs_bf = (u16*)(wsb + off);
  u16* imgsT   = (u16*)(wsb + off);
  off += (size_t)BB * 2048 * PPAD * 2;                                  // 27.26 MB
  u16* W3_bf   = (u16*)(wsb + off); off += (size_t)4608 * DEC * 2;      // 4.72 MB
  u16* Wih_bf  = (u16*)(wsb + off); off += (size_t)G4 * KX * 2;         // 10.49 MB
  u16* fcW_bf  = (u16*)(wsb + off); off += (size_t)VVP * DEC * 2;       // 10.49 MB
  u16* encW_bf = (u16*)(wsb + off); off += (size_t)ATT * ENC * 2;       // 2.00 MB
  u16* att1    = (u16*)(wsb + off);
  u16* W2_bf   = att1;                      // aliased (consumed before att1 write)
  u16* mean_bf = att1 + (size_t)1024 * ENC;
  off += (size_t)BB * PP * ATT * 2;                                     // 6.42 MB
  u16* xemb    = (u16*)(wsb + off); off += (size_t)BB * TT * EMB * 2;   // 4.19 MB
  u16* h_hist  = (u16*)(wsb + off); off += (size_t)BB * TT * DEC * 2;   // 4.19 MB
  u16* ge      = (u16*)(wsb + off); off += (size_t)BB * TT * G4 * 2;    // 16.78 MB
  u16* h_chunk = (u16*)(wsb + off); off += (size_t)BB * DEC * 2;
  float* c      = (float*)(wsb + off); off += (size_t)BB * DEC * 4;
  float* att2   = (float*)(wsb + off); off += (size_t)BB * ATT * 4;
  float* gatev  = (float*)(wsb + off); off += (size_t)BB * ENC * 4;
  float* hWhh   = (float*)(wsb + off); off += (size_t)BB * G4 * 4;
  u16* x_aweL   = (u16*)(wsb + off); off += (size_t)BB * ENC * 2;
  u32* bar      = (u32*)(wsb + off); off += (size_t)32768 * 4;          // 128KB flags

  // one-time conversions + hoists
  k_cvt<<<(BB * PP * ENC) / 2048, 256, 0, stream>>>(imgs, imgs_bf, BB * PP * ENC);
  k_cvt<<<(DEC * DEC) / 2048, 256, 0, stream>>>(decW, W3_bf, DEC * DEC);
  k_cvt<<<(ENC * DEC) / 2048, 256, 0, stream>>>(fbW, W3_bf + (size_t)DEC * DEC, ENC * DEC);
  k_cvt<<<(G4 * DEC) / 2048, 256, 0, stream>>>(Whh, W3_bf + (size_t)(DEC + ENC) * DEC, G4 * DEC);
  k_cvt<<<(G4 * KX) / 2048, 256, 0, stream>>>(Wih, Wih_bf, G4 * KX);
  k_cvt<<<(VV * DEC) / 2048, 256, 0, stream>>>(fcW, fcW_bf, VV * DEC);
  k_cvt<<<(ATT * ENC) / 2048, 256, 0, stream>>>(encW, encW_bf, ATT * ENC);
  k_cvt<<<(DEC * ENC) / 2048, 256, 0, stream>>>(ihW, W2_bf, DEC * ENC);
  k_cvt<<<(DEC * ENC) / 2048, 256, 0, stream>>>(icW, W2_bf + (size_t)DEC * ENC, DEC * ENC);
  k_emball<<<(BB * TT * EMB / 8) / 256, 256, 0, stream>>>(bx, embW, xemb);
  k_gemb<<<dim3((BB * TT) / 32, 4), 256, 0, stream>>>(Wih_bf, xemb, ge);

  k_mean<<<BB * 4, 256, 0, stream>>>(imgs_bf, mean_bf);
  k_init2<<<64, 64, 0, stream>>>(W2_bf, ihb, icb, mean_bf, h_chunk, c);
  k_att1<<<(BB * PP) / 32, 256, 0, stream>>>(imgs_bf, encW_bf, encb, att1);
  // transpose AFTER all imgs_bf readers (overwrites aliased region)
  k_timg<<<32 * 256, 256, 0, stream>>>(imgs, imgsT);
  k_zero<<<128, 256, 0, stream>>>(bar, 32768);

  // persistent recurrence
  k_mega<<<NWG, 256, 0, stream>>>(bxlen, W3_bf, decb, fbb, att1, faW, fab,
                                  imgsT, Wih_bf, ge, bih, bhh,
                                  h_chunk, c, h_hist, att2, gatev, hWhh,
                                  x_aweL, out_alphas, bar);

  // batched fc over all (b,t)
  k_fcall<<<dim3((BB * TT) / 32, 20), 256, 0, stream>>>(bxlen, fcW_bf, fcb, h_hist, out_preds);
}

// Round 7
// 7097.919 us; speedup vs baseline: 1.5989x; 1.1829x over previous
//
#include <hip/hip_runtime.h>
#include <hip/hip_bf16.h>

#define BB 32
#define TT 128
#define PP 196
#define PPAD 208
#define ENC 2048
#define DEC 512
#define ATT 512
#define EMB 512
#define VV 10000
#define VVP 10240
#define G4 2048
#define KX 2560
#define NWG 256

typedef unsigned short u16;
typedef unsigned int u32;
typedef __attribute__((ext_vector_type(8))) short short8;
typedef __attribute__((ext_vector_type(4))) float f32x4;

__device__ __forceinline__ float bf2f(u16 u) { return __uint_as_float(((u32)u) << 16); }
__device__ __forceinline__ u16 f2bf(float f) {
  u32 x = __float_as_uint(f);
  u32 r = (x + 0x7fffu + ((x >> 16) & 1u)) >> 16;
  return (u16)r;
}
__device__ __forceinline__ void unpack8(uint4 v, float* f) {
  f[0] = __uint_as_float(v.x << 16); f[1] = __uint_as_float(v.x & 0xffff0000u);
  f[2] = __uint_as_float(v.y << 16); f[3] = __uint_as_float(v.y & 0xffff0000u);
  f[4] = __uint_as_float(v.z << 16); f[5] = __uint_as_float(v.z & 0xffff0000u);
  f[6] = __uint_as_float(v.w << 16); f[7] = __uint_as_float(v.w & 0xffff0000u);
}
__device__ __forceinline__ void load8(const float* __restrict__ p, float* f) {
  float4 a = ((const float4*)p)[0];
  float4 b = ((const float4*)p)[1];
  f[0] = a.x; f[1] = a.y; f[2] = a.z; f[3] = a.w;
  f[4] = b.x; f[5] = b.y; f[6] = b.z; f[7] = b.w;
}
__device__ __forceinline__ float sigf(float x) { return 1.0f / (1.0f + __expf(-x)); }
__device__ __forceinline__ short8 ld_frag(const u16* __restrict__ p) {
  union { uint4 u; short8 s; } cv;
  cv.u = *(const uint4*)p;
  return cv.s;
}

// ---- device-scope relaxed atomics (LLC-coherent, bypass non-coherent L2) ----
__device__ __forceinline__ void ast_f32(float* p, float v) {
  __hip_atomic_store(p, v, __ATOMIC_RELAXED, __HIP_MEMORY_SCOPE_AGENT);
}
__device__ __forceinline__ float ald_f32(const float* p) {
  return __hip_atomic_load((float*)p, __ATOMIC_RELAXED, __HIP_MEMORY_SCOPE_AGENT);
}
__device__ __forceinline__ u32 ald_u32(const u32* p) {
  return __hip_atomic_load((u32*)p, __ATOMIC_RELAXED, __HIP_MEMORY_SCOPE_AGENT);
}
__device__ __forceinline__ void ast_u32(u32* p, u32 v) {
  __hip_atomic_store(p, v, __ATOMIC_RELAXED, __HIP_MEMORY_SCOPE_AGENT);
}
__device__ __forceinline__ void ast_u16(u16* p, u16 v) {
  __hip_atomic_store(p, v, __ATOMIC_RELAXED, __HIP_MEMORY_SCOPE_AGENT);
}
__device__ __forceinline__ void wait_ge(u32* p, u32 tag) {
  long sp = 0;
  while (ald_u32(p) < tag) {
    __builtin_amdgcn_s_sleep(2);
    if (++sp > (1L << 21)) break;   // bounded bailout
  }
}

// chunk-linear addressing (chunk = one lane's ds_read_b128 payload)
__device__ __forceinline__ int hadr(int b, int d) {
  return ((((b >> 4) << 10) + ((d >> 5) << 6) + (((d >> 3) & 3) << 4) + (b & 15)) << 3) + (d & 7);
}
__device__ __forceinline__ int xadr(int b, int ch) {
  return ((((b >> 4) << 12) + ((ch >> 5) << 6) + (((ch >> 3) & 3) << 4) + (b & 15)) << 3) + (ch & 7);
}

// flag offsets in the bar array (dwords; per-flag stride 32 dwords = 128B)
#define F_P1   0        // 72 flags
#define F_XD   4096     // 256 flags
#define F_PART 16384    // 32 flags
#define F_HD   18432    // 32 flags
#define F_G1   20480    // 8 replicas
#define F_G3   21504    // 8 replicas

// ---------- one-time f32 -> bf16 conversion ----------
__global__ __launch_bounds__(256) void k_cvt(const float* __restrict__ src, u16* __restrict__ dst, int n) {
  int i0 = (blockIdx.x * 256 + threadIdx.x) * 8;
  if (i0 >= n) return;
  float f[8]; load8(src + i0, f);
  u16 o[8];
#pragma unroll
  for (int u = 0; u < 8; u++) o[u] = f2bf(f[u]);
  *(uint4*)(dst + i0) = *(const uint4*)o;
}

// ---------- one-time: gather emb rows -> xemb bf16 (4096 x 512) ----------
__global__ __launch_bounds__(256) void k_emball(const int* __restrict__ bx,
    const float* __restrict__ embW, u16* __restrict__ xemb) {
  int flat = blockIdx.x * 256 + threadIdx.x;
  int row = flat >> 6;
  int c8 = (flat & 63) * 8;
  int tok = bx[row];
  const float* e = embW + (size_t)tok * EMB + c8;
  float f[8]; load8(e, f);
  u16 o[8];
#pragma unroll
  for (int u = 0; u < 8; u++) o[u] = f2bf(f[u]);
  *(uint4*)(xemb + (size_t)row * EMB + c8) = *(const uint4*)o;
}

// ---------- one-time: transpose imgs f32 -> imgsT bf16 [b][ch][p(pad 208)] ----------
__global__ __launch_bounds__(256) void k_timg(const float* __restrict__ imgs, u16* __restrict__ imgsT) {
  int b = blockIdx.x >> 8;
  int sub = blockIdx.x & 255;
  int flat = sub * 256 + threadIdx.x;
  int ch = flat >> 5, pg = flat & 31;
  if (pg >= 26) return;
  u16 o[8];
#pragma unroll
  for (int j = 0; j < 8; j++) {
    int p = pg * 8 + j;
    float v = (p < PP) ? imgs[((size_t)b * PP + p) * ENC + ch] : 0.f;
    o[j] = f2bf(v);
  }
  *(uint4*)(imgsT + ((size_t)b * 2048 + ch) * PPAD + pg * 8) = *(const uint4*)o;
}

// ---------- mean over p ----------
__global__ __launch_bounds__(256) void k_mean(const u16* __restrict__ imgs_bf, u16* __restrict__ mean_bf) {
  int b = blockIdx.x >> 2, chunk = blockIdx.x & 3;
  int ch0 = chunk * 512 + threadIdx.x * 2;
  const u32* base = (const u32*)(imgs_bf + (size_t)b * PP * ENC + ch0);
  float a0 = 0.f, a1 = 0.f;
#pragma unroll 4
  for (int p = 0; p < PP; p++) {
    u32 u = base[(size_t)p * (ENC / 2)];
    a0 += __uint_as_float(u << 16);
    a1 += __uint_as_float(u & 0xffff0000u);
  }
  const float inv = 1.0f / PP;
  u16 o[2] = { f2bf(a0 * inv), f2bf(a1 * inv) };
  *(u32*)(mean_bf + b * ENC + ch0) = *(const u32*)o;
}

// ---------- init via MFMA: h0 (chunk layout) and c0 ----------
__global__ __launch_bounds__(64) void k_init2(const u16* __restrict__ W2_bf,
    const float* __restrict__ ihb, const float* __restrict__ icb,
    const u16* __restrict__ mean_bf, u16* __restrict__ h_chunk, float* __restrict__ c) {
  int lane = threadIdx.x;
  int j0 = blockIdx.x * 16;
  int m = lane & 15, quad = lane >> 4;
  const u16* arow = W2_bf + (size_t)(j0 + m) * ENC + quad * 8;
  const u16* xb0 = mean_bf + (size_t)m * ENC + quad * 8;
  const u16* xb1 = mean_bf + (size_t)(16 + m) * ENC + quad * 8;
  f32x4 acc0 = {0.f,0.f,0.f,0.f}, acc1 = {0.f,0.f,0.f,0.f};
  for (int k = 0; k < ENC; k += 32) {
    short8 a = ld_frag(arow + k);
    short8 x0 = ld_frag(xb0 + k);
    short8 x1 = ld_frag(xb1 + k);
    acc0 = __builtin_amdgcn_mfma_f32_16x16x32_bf16(a, x0, acc0, 0, 0, 0);
    acc1 = __builtin_amdgcn_mfma_f32_16x16x32_bf16(a, x1, acc1, 0, 0, 0);
  }
  int jj = j0 + quad * 4;
  int b0 = m, b1 = 16 + m;
#pragma unroll
  for (int r = 0; r < 4; r++) {
    int j = jj + r;
    if (j < 512) {
      float bia = ihb[j];
      h_chunk[hadr(b0, j)] = f2bf(acc0[r] + bia);
      h_chunk[hadr(b1, j)] = f2bf(acc1[r] + bia);
    } else {
      int g = j - 512;
      float bia = icb[g];
      c[b0 * DEC + g] = acc0[r] + bia;
      c[b1 * DEC + g] = acc1[r] + bia;
    }
  }
}

// ---------- att1 via MFMA ----------
__global__ __launch_bounds__(256) void k_att1(const u16* __restrict__ imgs_bf,
    const u16* __restrict__ encW_bf, const float* __restrict__ encb, u16* __restrict__ att1) {
  int tid = threadIdx.x;
  int wave = tid >> 6, lane = tid & 63;
  int m0 = blockIdx.x * 32;
  int lm = lane & 15, quad = lane >> 4;
  const u16* b0p = imgs_bf + (size_t)(m0 + lm) * ENC + quad * 8;
  const u16* b1p = imgs_bf + (size_t)(m0 + 16 + lm) * ENC + quad * 8;
  const u16* arow = encW_bf + (size_t)(wave * 128 + lm) * ENC + quad * 8;
  f32x4 acc[8][2];
#pragma unroll
  for (int i = 0; i < 8; i++) { acc[i][0] = (f32x4){0.f,0.f,0.f,0.f}; acc[i][1] = (f32x4){0.f,0.f,0.f,0.f}; }
  for (int k = 0; k < ENC; k += 32) {
    short8 B0 = ld_frag(b0p + k);
    short8 B1 = ld_frag(b1p + k);
#pragma unroll
    for (int i = 0; i < 8; i++) {
      short8 A = ld_frag(arow + (size_t)i * 16 * ENC + k);
      acc[i][0] = __builtin_amdgcn_mfma_f32_16x16x32_bf16(A, B0, acc[i][0], 0, 0, 0);
      acc[i][1] = __builtin_amdgcn_mfma_f32_16x16x32_bf16(A, B1, acc[i][1], 0, 0, 0);
    }
  }
#pragma unroll
  for (int i = 0; i < 8; i++) {
    int jb = wave * 128 + i * 16 + quad * 4;
#pragma unroll
    for (int r = 0; r < 4; r++) {
      int j = jb + r;
      float bia = encb[j];
      att1[(size_t)(m0 + lm) * ATT + j]      = f2bf(acc[i][0][r] + bia);
      att1[(size_t)(m0 + 16 + lm) * ATT + j] = f2bf(acc[i][1][r] + bia);
    }
  }
}

// ---------- one-time: ge = xemb @ Wih[:, :512]^T in interleaved gate order ----------
__global__ __launch_bounds__(256) void k_gemb(const u16* __restrict__ Wih_bf,
    const u16* __restrict__ xemb, u16* __restrict__ ge) {
  int tid = threadIdx.x;
  int wave = tid >> 6, lane = tid & 63;
  int m0 = blockIdx.x * 32;
  int jbase = blockIdx.y * 512 + wave * 128;
  int lm = lane & 15, quad = lane >> 4;
  const u16* b0p = xemb + ((size_t)(m0 + lm) << 9) + (quad << 3);
  const u16* b1p = xemb + ((size_t)(m0 + 16 + lm) << 9) + (quad << 3);
  const u16* arow = Wih_bf + (size_t)(jbase + lm) * KX + (quad << 3);
  f32x4 acc[8][2];
#pragma unroll
  for (int i = 0; i < 8; i++) { acc[i][0] = (f32x4){0.f,0.f,0.f,0.f}; acc[i][1] = (f32x4){0.f,0.f,0.f,0.f}; }
  for (int k = 0; k < 512; k += 32) {
    short8 B0 = ld_frag(b0p + k);
    short8 B1 = ld_frag(b1p + k);
#pragma unroll
    for (int i = 0; i < 8; i++) {
      short8 A = ld_frag(arow + (size_t)i * 16 * KX + k);
      acc[i][0] = __builtin_amdgcn_mfma_f32_16x16x32_bf16(A, B0, acc[i][0], 0, 0, 0);
      acc[i][1] = __builtin_amdgcn_mfma_f32_16x16x32_bf16(A, B1, acc[i][1], 0, 0, 0);
    }
  }
#pragma unroll
  for (int i = 0; i < 8; i++) {
#pragma unroll
    for (int r = 0; r < 4; r++) {
      int j = jbase + i * 16 + quad * 4 + r;
      int d = j & 511, g9 = j >> 9;
      int jq = ((d >> 2) << 4) + (g9 << 2) + (d & 3);
      ge[((size_t)(m0 + lm)) * G4 + jq]      = f2bf(acc[i][0][r]);
      ge[((size_t)(m0 + 16 + lm)) * G4 + jq] = f2bf(acc[i][1][r]);
    }
  }
}

// ---------- barrier state init ----------
__global__ __launch_bounds__(256) void k_zero(unsigned* p, int n) {
  int i = blockIdx.x * 256 + threadIdx.x;
  if (i < n) p[i] = 0u;
}

// ---------- persistent mega-kernel: flag pipeline + weights pinned in VGPRs ----------
// wgs 0-71:  P1 (wait gen3) -> flag p1d; then P23 -> flag xd   [W3 tile in regs]
// wgs 72-223: P23 (wait gen1) -> flag xd
// wgs 224-255: P23 -> flag xd -> mini-bar2 -> P4 -> flag hd    [Wih tile in regs]
// wg255: gen1 leader (idle in P1). wg0: gen3 leader (idle in P4).
__global__ __launch_bounds__(256, 1) void k_mega(
    const int* __restrict__ bxlen,
    const u16* __restrict__ W3,
    const float* __restrict__ decb, const float* __restrict__ fbb,
    const u16* __restrict__ att1, const float* __restrict__ faW, const float* __restrict__ fab,
    const u16* __restrict__ imgsT, const u16* __restrict__ Wih_bf, const u16* __restrict__ ge,
    const float* __restrict__ bih, const float* __restrict__ bhh,
    u16* __restrict__ h_chunk, float* __restrict__ c_glob, u16* __restrict__ h_hist,
    float* __restrict__ att2, float* __restrict__ gatev, float* __restrict__ hWhh,
    u16* __restrict__ x_aweL,
    float* __restrict__ out_alphas,
    u32* __restrict__ bar) {
  const int wg = blockIdx.x;
  const int tid = threadIdx.x;
  const int wid = tid >> 6, lane = tid & 63;
  const int m = lane & 15, quad = lane >> 4;
  const bool isP1 = (wg < 72);
  const bool isP4 = (wg >= 224);
  const int q4 = wg - 224;

  __shared__ __align__(16) u16 uSX[65536];      // 128KB: P1 stages h (32KB), P4 stages x_awe (128KB)
  __shared__ float sG[4][16][33];
  __shared__ float sA[512], sW[512];
  __shared__ float sAl[PPAD];
  __shared__ float sR[4], sR2[4];

  const float fab0 = fab[0];
  const int b_g = wg >> 3, s_g = wg & 7;
  const int len_g = bxlen[b_g];
  int len4 = 0, b4 = 0, dl4 = 0;
  float c_reg[4] = {0.f, 0.f, 0.f, 0.f};
  if (isP4 && tid < 128) {
    b4 = tid & 31; dl4 = tid >> 5;
    len4 = bxlen[b4];
#pragma unroll
    for (int r = 0; r < 4; r++) c_reg[r] = c_glob[(b4 << 9) + (q4 << 4) + (dl4 << 2) + r];
  }

  // ---- preload per-wave weight tiles into VGPRs (invariant across t) ----
  short8 wA[16];   // P1: 16 j x 512 K tile (64 VGPR)
  short8 wG[64];   // P4: 16 j x 2048 K tile (256 VGPR)
  if (isP1) {
    int gw = (wg << 2) + wid;
    int j0 = gw << 4;
    const u16* arow = W3 + ((size_t)(j0 + m) << 9) + (quad << 3);
#pragma unroll
    for (int k = 0; k < 16; k++) wA[k] = ld_frag(arow + k * 32);
  }
  if (isP4) {
    const int row0 = (wid << 9) + (q4 << 4);
    const u16* arow = Wih_bf + (size_t)(row0 + m) * KX + 512 + (quad << 3);
#pragma unroll
    for (int k = 0; k < 64; k++) wG[k] = ld_frag(arow + (k << 5));
  }

  for (int i = tid; i < 512; i += 256) sW[i] = faW[i];
  __syncthreads();

  for (int t = 0; t < TT; t++) {
    const u32 tag = (u32)(t + 1);

    // ================= P1 (wgs 0-71) =================
    if (isP1) {
      if (t > 0 && wg != 0) {
        if (tid == 0) wait_ge(bar + F_G3 + (wg & 7) * 32, (u32)t);
        __syncthreads();
      }
      // stage h (chunk-linear, atomic dwords)
      {
        const u32* src = (const u32*)h_chunk;
        u32* dstw = (u32*)uSX;
#pragma unroll
        for (int i = 0; i < 8; i++) {
          int d4i = ((i << 8) + tid) << 2;
          u32 w0 = ald_u32(src + d4i), w1 = ald_u32(src + d4i + 1);
          u32 w2 = ald_u32(src + d4i + 2), w3 = ald_u32(src + d4i + 3);
          uint4 v = {w0, w1, w2, w3};
          *(uint4*)(dstw + d4i) = v;
        }
      }
      __syncthreads();
      int gw = (wg << 2) + wid;
      int j0 = gw << 4;
      f32x4 acc0 = {0.f,0.f,0.f,0.f}, acc1 = {0.f,0.f,0.f,0.f};
#pragma unroll
      for (int k = 0; k < 16; k++) {
        short8 x0 = ld_frag(uSX + (((k << 6) + lane) << 3));
        short8 x1 = ld_frag(uSX + 8192 + (((k << 6) + lane) << 3));
        acc0 = __builtin_amdgcn_mfma_f32_16x16x32_bf16(wA[k], x0, acc0, 0, 0, 0);
        acc1 = __builtin_amdgcn_mfma_f32_16x16x32_bf16(wA[k], x1, acc1, 0, 0, 0);
      }
      int jj = j0 + (quad << 2);
      int b0 = m, b1 = 16 + m;
      if (j0 < 512) {
#pragma unroll
        for (int r = 0; r < 4; r++) {
          int j = jj + r; float bia = decb[j];
          ast_f32(&att2[(b0 << 9) + j], acc0[r] + bia);
          ast_f32(&att2[(b1 << 9) + j], acc1[r] + bia);
        }
      } else if (j0 < 2560) {
#pragma unroll
        for (int r = 0; r < 4; r++) {
          int g = jj + r - 512; float bia = fbb[g];
          ast_f32(&gatev[(b0 << 11) + g], sigf(acc0[r] + bia));
          ast_f32(&gatev[(b1 << 11) + g], sigf(acc1[r] + bia));
        }
      } else {
#pragma unroll
        for (int r = 0; r < 4; r++) {
          int j = jj + r - 2560;
          ast_f32(&hWhh[(b0 << 11) + j], acc0[r]);
          ast_f32(&hWhh[(b1 << 11) + j], acc1[r]);
        }
      }
      __syncthreads();                       // drain stores (vmcnt) before flag
      if (tid == 0) ast_u32(bar + F_P1 + wg * 32, tag);
    }

    // ================= gen1: P1 done =================
    if (wg == 255) {
      if (wid == 0) {
        long sp = 0;
        while (true) {
          u32 a = ald_u32(bar + F_P1 + lane * 32);                      // flags 0-63
          u32 b2 = (lane < 8) ? ald_u32(bar + F_P1 + (lane + 64) * 32) : 0xffffffffu;
          bool ok = (a >= tag) && (b2 >= tag);
          if (__ballot(ok) == ~0ULL) break;
          __builtin_amdgcn_s_sleep(2);
          if (++sp > (1L << 21)) break;
        }
        if (lane == 0)
          for (int r2 = 0; r2 < 8; r2++) ast_u32(bar + F_G1 + r2 * 32, tag);
      }
      __syncthreads();
    } else {
      if (tid == 0) wait_ge(bar + F_G1 + (wg & 7) * 32, tag);
      __syncthreads();
    }

    // ================= P23: e + softmax + awe (all wgs, 8/b) =================
    if (t < len_g) {
      for (int i = tid; i < 512; i += 256) sA[i] = ald_f32(&att2[(b_g << 9) + i]);
      float gch = ald_f32(&gatev[(b_g << 11) + (s_g << 8) + tid]);
      __syncthreads();
      float e_t = -1e30f;
      if (tid < PP) {
        const uint4* ar = (const uint4*)(att1 + ((size_t)(b_g * PP + tid) << 9));
        float acc = 0.f;
#pragma unroll 8
        for (int k = 0; k < 512; k += 8) {
          float af[8]; unpack8(ar[k >> 3], af);
#pragma unroll
          for (int u = 0; u < 8; u++) {
            float v = af[u] + sA[k + u];
            acc += fmaxf(v, 0.f) * sW[k + u];
          }
        }
        e_t = acc + fab0;
      }
      float wmax = e_t;
#pragma unroll
      for (int off = 32; off; off >>= 1) wmax = fmaxf(wmax, __shfl_xor(wmax, off));
      if (lane == 0) sR[wid] = wmax;
      __syncthreads();
      float mx = fmaxf(fmaxf(sR[0], sR[1]), fmaxf(sR[2], sR[3]));
      float ex = (tid < PP) ? __expf(e_t - mx) : 0.f;
      float wsum = ex;
#pragma unroll
      for (int off = 32; off; off >>= 1) wsum += __shfl_xor(wsum, off);
      if (lane == 0) sR2[wid] = wsum;
      __syncthreads();
      float inv = 1.0f / (sR2[0] + sR2[1] + sR2[2] + sR2[3]);
      float al = ex * inv;
      if (tid < PP) {
        sAl[tid] = al;
        if (s_g == 0) out_alphas[((size_t)b_g * TT + t) * PP + tid] = al;
      } else if (tid < PPAD) {
        sAl[tid] = 0.f;
      }
      __syncthreads();
      int ch = (s_g << 8) + tid;
      const uint4* ip = (const uint4*)(imgsT + ((size_t)(b_g * 2048 + ch)) * PPAD);
      float acc = 0.f;
#pragma unroll
      for (int pg = 0; pg < 26; pg++) {
        uint4 v = ip[pg];
        float f[8]; unpack8(v, f);
#pragma unroll
        for (int u = 0; u < 8; u++) acc += sAl[pg * 8 + u] * f[u];
      }
      ast_u16(&x_aweL[xadr(b_g, ch)], f2bf(gch * acc));
    } else {
      if (s_g == 0 && tid < PP) out_alphas[((size_t)b_g * TT + t) * PP + tid] = 0.f;
    }
    __syncthreads();                       // drain x_awe stores before flag
    if (tid == 0) ast_u32(bar + F_XD + wg * 32, tag);

    // ================= P4 (wgs 224-255): mini-bar2 + gates GEMM + LSTM =================
    if (isP4) {
      if (wid == 0) {
        long sp = 0;
        while (true) {                    // my 8-wg slice of xd
          bool ok = true;
          if (lane < 8) ok = ald_u32(bar + F_XD + (q4 * 8 + lane) * 32) >= tag;
          if (__ballot(ok) == ~0ULL) break;
          __builtin_amdgcn_s_sleep(2);
          if (++sp > (1L << 21)) break;
        }
        if (lane == 0) ast_u32(bar + F_PART + q4 * 32, tag);
        sp = 0;
        while (true) {                    // all 32 parts
          bool ok = true;
          if (lane < 32) ok = ald_u32(bar + F_PART + lane * 32) >= tag;
          if (__ballot(ok) == ~0ULL) break;
          __builtin_amdgcn_s_sleep(2);
          if (++sp > (1L << 21)) break;
        }
      }
      __syncthreads();
      // stage full x_awe (128KB) chunk-linear -> LDS linear
      {
        const u32* src = (const u32*)x_aweL;
        u32* dstw = (u32*)uSX;
#pragma unroll 8
        for (int i = 0; i < 32; i++) {
          int d4i = ((i << 8) + tid) << 2;
          u32 w0 = ald_u32(src + d4i), w1 = ald_u32(src + d4i + 1);
          u32 w2 = ald_u32(src + d4i + 2), w3 = ald_u32(src + d4i + 3);
          uint4 v = {w0, w1, w2, w3};
          *(uint4*)(dstw + d4i) = v;
        }
      }
      __syncthreads();
      f32x4 acc0 = {0.f,0.f,0.f,0.f}, acc1 = {0.f,0.f,0.f,0.f};
#pragma unroll
      for (int k = 0; k < 64; k++) {
        short8 x0 = ld_frag(uSX + (((k << 6) + lane) << 3));
        short8 x1 = ld_frag(uSX + 32768 + (((k << 6) + lane) << 3));
        acc0 = __builtin_amdgcn_mfma_f32_16x16x32_bf16(wG[k], x0, acc0, 0, 0, 0);
        acc1 = __builtin_amdgcn_mfma_f32_16x16x32_bf16(wG[k], x1, acc1, 0, 0, 0);
      }
#pragma unroll
      for (int r = 0; r < 4; r++) {
        int jl = (quad << 2) + r;
        sG[wid][jl][m] = acc0[r];
        sG[wid][jl][16 + m] = acc1[r];
      }
      __syncthreads();
      if (tid < 128 && t < len4) {
        const u16* gep = ge + ((size_t)b4 * TT + t) * G4 + ((((q4 << 2) + dl4)) << 4);
        uint4 gv0 = *(const uint4*)gep;
        uint4 gv1 = *(const uint4*)(gep + 8);
        float gef[16];
        unpack8(gv0, gef);
        unpack8(gv1, gef + 8);
        float pre[4][4];
#pragma unroll
        for (int rr = 0; rr < 4; rr++) {
          int dloc = (dl4 << 2) + rr;
          int d = (q4 << 4) + dloc;
#pragma unroll
          for (int g = 0; g < 4; g++) {
            int j = (g << 9) + d;
            pre[rr][g] = sG[g][dloc][b4] + gef[(g << 2) + rr]
                       + ald_f32(&hWhh[(b4 << 11) + j]) + bih[j] + bhh[j];
          }
        }
#pragma unroll
        for (int rr = 0; rr < 4; rr++) {
          int d = (q4 << 4) + (dl4 << 2) + rr;
          float i_ = sigf(pre[rr][0]);
          float f_ = sigf(pre[rr][1]);
          float g_ = tanhf(pre[rr][2]);
          float o_ = sigf(pre[rr][3]);
          float cn = f_ * c_reg[rr] + i_ * g_;
          float hn = o_ * tanhf(cn);
          c_reg[rr] = cn;
          u16 hb = f2bf(hn);
          ast_u16(&h_chunk[hadr(b4, d)], hb);
          h_hist[((size_t)b4 * TT + t) * DEC + d] = hb;
        }
      }
      __syncthreads();                     // drain h stores before flag
      if (tid == 0) ast_u32(bar + F_HD + q4 * 32, tag);
    }

    // ================= gen3: h done (leader wg0, idle during P4) =================
    if (wg == 0) {
      if (wid == 0) {
        long sp = 0;
        while (true) {
          bool ok = true;
          if (lane < 32) ok = ald_u32(bar + F_HD + lane * 32) >= tag;
          if (__ballot(ok) == ~0ULL) break;
          __builtin_amdgcn_s_sleep(2);
          if (++sp > (1L << 21)) break;
        }
        if (lane == 0)
          for (int r2 = 0; r2 < 8; r2++) ast_u32(bar + F_G3 + r2 * 32, tag);
      }
      __syncthreads();
    }
  }
}

// ---------- batched fc ----------
__global__ __launch_bounds__(256) void k_fcall(const int* __restrict__ bxlen,
    const u16* __restrict__ fcW_bf, const float* __restrict__ fcb,
    const u16* __restrict__ h_hist, float* __restrict__ preds) {
  int tid = threadIdx.x;
  int wave = tid >> 6, lane = tid & 63;
  int m0 = blockIdx.x * 32;
  int jbase = blockIdx.y * 512 + wave * 128;
  int lm = lane & 15, quad = lane >> 4;
  const u16* b0p = h_hist + (size_t)(m0 + lm) * DEC + quad * 8;
  const u16* b1p = h_hist + (size_t)(m0 + 16 + lm) * DEC + quad * 8;
  const u16* arow = fcW_bf + (size_t)(jbase + lm) * DEC + quad * 8;
  f32x4 acc[8][2];
#pragma unroll
  for (int i = 0; i < 8; i++) { acc[i][0] = (f32x4){0.f,0.f,0.f,0.f}; acc[i][1] = (f32x4){0.f,0.f,0.f,0.f}; }
  for (int k = 0; k < DEC; k += 32) {
    short8 B0 = ld_frag(b0p + k);
    short8 B1 = ld_frag(b1p + k);
#pragma unroll
    for (int i = 0; i < 8; i++) {
      short8 A = ld_frag(arow + (size_t)i * 16 * DEC + k);
      acc[i][0] = __builtin_amdgcn_mfma_f32_16x16x32_bf16(A, B0, acc[i][0], 0, 0, 0);
      acc[i][1] = __builtin_amdgcn_mfma_f32_16x16x32_bf16(A, B1, acc[i][1], 0, 0, 0);
    }
  }
  int row0 = m0 + lm, row1 = m0 + 16 + lm;
  bool act0 = ((row0 & 127) < bxlen[row0 >> 7]);
  bool act1 = ((row1 & 127) < bxlen[row1 >> 7]);
#pragma unroll
  for (int i = 0; i < 8; i++) {
    int jb = jbase + i * 16 + quad * 4;
#pragma unroll
    for (int r = 0; r < 4; r++) {
      int j = jb + r;
      if (j < VV) {
        float bia = fcb[j];
        preds[(size_t)row0 * VV + j] = act0 ? (acc[i][0][r] + bia) : 0.f;
        preds[(size_t)row1 * VV + j] = act1 ? (acc[i][1][r] + bia) : 0.f;
      }
    }
  }
}

extern "C" void kernel_launch(void* const* d_in, const int* in_sizes, int n_in,
                              void* d_out, int out_size, void* d_ws, size_t ws_size,
                              hipStream_t stream) {
  const float* imgs = (const float*)d_in[0];
  const int* bx     = (const int*)d_in[1];
  const int* bxlen  = (const int*)d_in[2];
  const float* embW = (const float*)d_in[3];
  const float* encW = (const float*)d_in[4];
  const float* encb = (const float*)d_in[5];
  const float* decW = (const float*)d_in[6];
  const float* decb = (const float*)d_in[7];
  const float* faW  = (const float*)d_in[8];
  const float* fab  = (const float*)d_in[9];
  const float* ihW  = (const float*)d_in[10];
  const float* ihb  = (const float*)d_in[11];
  const float* icW  = (const float*)d_in[12];
  const float* icb  = (const float*)d_in[13];
  const float* fbW  = (const float*)d_in[14];
  const float* fbb  = (const float*)d_in[15];
  const float* Wih  = (const float*)d_in[16];
  const float* bih  = (const float*)d_in[17];
  const float* Whh  = (const float*)d_in[18];
  const float* bhh  = (const float*)d_in[19];
  const float* fcW  = (const float*)d_in[20];
  const float* fcb  = (const float*)d_in[21];

  float* out_preds  = (float*)d_out;
  float* out_alphas = out_preds + (size_t)BB * TT * VV;

  char* wsb = (char*)d_ws;
  size_t off = 0;
  // region 0: imgs_bf (setup) ALIASED with imgsT (mega); imgsT written after all imgs_bf readers
  u16* imgs_bf = (u16*)(wsb + off);
  u16* imgsT   = (u16*)(wsb + off);
  off += (size_t)BB * 2048 * PPAD * 2;                                  // 27.26 MB
  u16* W3_bf   = (u16*)(wsb + off); off += (size_t)4608 * DEC * 2;      // 4.72 MB
  u16* Wih_bf  = (u16*)(wsb + off); off += (size_t)G4 * KX * 2;         // 10.49 MB
  u16* fcW_bf  = (u16*)(wsb + off); off += (size_t)VVP * DEC * 2;       // 10.49 MB
  u16* encW_bf = (u16*)(wsb + off); off += (size_t)ATT * ENC * 2;       // 2.00 MB
  u16* att1    = (u16*)(wsb + off);
  u16* W2_bf   = att1;                      // aliased (consumed before att1 write)
  u16* mean_bf = att1 + (size_t)1024 * ENC;
  off += (size_t)BB * PP * ATT * 2;                                     // 6.42 MB
  u16* xemb    = (u16*)(wsb + off); off += (size_t)BB * TT * EMB * 2;   // 4.19 MB
  u16* h_hist  = (u16*)(wsb + off); off += (size_t)BB * TT * DEC * 2;   // 4.19 MB
  u16* ge      = (u16*)(wsb + off); off += (size_t)BB * TT * G4 * 2;    // 16.78 MB
  u16* h_chunk = (u16*)(wsb + off); off += (size_t)BB * DEC * 2;
  float* c      = (float*)(wsb + off); off += (size_t)BB * DEC * 4;
  float* att2   = (float*)(wsb + off); off += (size_t)BB * ATT * 4;
  float* gatev  = (float*)(wsb + off); off += (size_t)BB * ENC * 4;
  float* hWhh   = (float*)(wsb + off); off += (size_t)BB * G4 * 4;
  u16* x_aweL   = (u16*)(wsb + off); off += (size_t)BB * ENC * 2;
  u32* bar      = (u32*)(wsb + off); off += (size_t)32768 * 4;          // 128KB flags

  // one-time conversions + hoists
  k_cvt<<<(BB * PP * ENC) / 2048, 256, 0, stream>>>(imgs, imgs_bf, BB * PP * ENC);
  k_cvt<<<(DEC * DEC) / 2048, 256, 0, stream>>>(decW, W3_bf, DEC * DEC);
  k_cvt<<<(ENC * DEC) / 2048, 256, 0, stream>>>(fbW, W3_bf + (size_t)DEC * DEC, ENC * DEC);
  k_cvt<<<(G4 * DEC) / 2048, 256, 0, stream>>>(Whh, W3_bf + (size_t)(DEC + ENC) * DEC, G4 * DEC);
  k_cvt<<<(G4 * KX) / 2048, 256, 0, stream>>>(Wih, Wih_bf, G4 * KX);
  k_cvt<<<(VV * DEC) / 2048, 256, 0, stream>>>(fcW, fcW_bf, VV * DEC);
  k_cvt<<<(ATT * ENC) / 2048, 256, 0, stream>>>(encW, encW_bf, ATT * ENC);
  k_cvt<<<(DEC * ENC) / 2048, 256, 0, stream>>>(ihW, W2_bf, DEC * ENC);
  k_cvt<<<(DEC * ENC) / 2048, 256, 0, stream>>>(icW, W2_bf + (size_t)DEC * ENC, DEC * ENC);
  k_emball<<<(BB * TT * EMB / 8) / 256, 256, 0, stream>>>(bx, embW, xemb);
  k_gemb<<<dim3((BB * TT) / 32, 4), 256, 0, stream>>>(Wih_bf, xemb, ge);

  k_mean<<<BB * 4, 256, 0, stream>>>(imgs_bf, mean_bf);
  k_init2<<<64, 64, 0, stream>>>(W2_bf, ihb, icb, mean_bf, h_chunk, c);
  k_att1<<<(BB * PP) / 32, 256, 0, stream>>>(imgs_bf, encW_bf, encb, att1);
  // transpose AFTER all imgs_bf readers (overwrites aliased region)
  k_timg<<<32 * 256, 256, 0, stream>>>(imgs, imgsT);
  k_zero<<<128, 256, 0, stream>>>(bar, 32768);

  // persistent recurrence
  k_mega<<<NWG, 256, 0, stream>>>(bxlen, W3_bf, decb, fbb, att1, faW, fab,
                                  imgsT, Wih_bf, ge, bih, bhh,
                                  h_chunk, c, h_hist, att2, gatev, hWhh,
                                  x_aweL, out_alphas, bar);

  // batched fc over all (b,t)
  k_fcall<<<dim3((BB * TT) / 32, 20), 256, 0, stream>>>(bxlen, fcW_bf, fcb, h_hist, out_preds);
}